// Round 13
// baseline (323.196 us; speedup 1.0000x reference)
//
#include <hip/hip_runtime.h>
#include <hip/hip_bf16.h>

#define NTOK 87040  // 1024 windows * 85 tokens

typedef __attribute__((ext_vector_type(8))) short bf16x8;
typedef __attribute__((ext_vector_type(4))) float f32x4;
typedef __attribute__((ext_vector_type(16))) float f32x16;

#define MFMA __builtin_amdgcn_mfma_f32_16x16x32_bf16
#define MFMA32 __builtin_amdgcn_mfma_f32_32x32x16_bf16

__device__ __forceinline__ unsigned short f2b(float f) {
  unsigned int u; __builtin_memcpy(&u, &f, 4);
  u += 0x7fffu + ((u >> 16) & 1u);  // RNE
  return (unsigned short)(u >> 16);
}
__device__ __forceinline__ float b2f(short s) {
  unsigned int u = ((unsigned int)(unsigned short)s) << 16;
  float f; __builtin_memcpy(&f, &u, 4);
  return f;
}
__device__ __forceinline__ bf16x8 ldg8(const short* p) { return *(const bf16x8*)p; }
__device__ __forceinline__ f32x16 zero16() {
  f32x16 z;
#pragma unroll
  for (int i = 0; i < 16; i++) z[i] = 0.f;
  return z;
}
__device__ __forceinline__ unsigned int pk2(float lo, float hi) {
  float2 t2; t2.x = lo; t2.y = hi;
  __hip_bfloat162 t = __float22bfloat162_rn(t2);
  unsigned int r; __builtin_memcpy(&r, &t, 4);
  return r;
}
__device__ __forceinline__ uint2 pk4(float a, float b, float c, float d) {
  uint2 r; r.x = pk2(a, b); r.y = pk2(c, d);
  return r;
}
// load 8 f32, convert to bf16x8 fragment (RNE, same as prep path)
__device__ __forceinline__ bf16x8 ldf8(const float* p) {
  float4 a = *(const float4*)p;
  float4 b = *(const float4*)(p + 4);
  unsigned int w[4] = {pk2(a.x, a.y), pk2(a.z, a.w), pk2(b.x, b.y), pk2(b.z, b.w)};
  bf16x8 o; __builtin_memcpy(&o, w, 16);
  return o;
}

// natural spatial row p -> window token index
__device__ __forceinline__ int tokmap(int p, int hsShift, int wsShift, int tokOff) {
  int HSm = (1 << hsShift) - 1;
  int w = p & HSm;
  int h = (p >> hsShift) & HSm;
  int b = p >> (2 * hsShift);
  int bi = h >> wsShift, bj = w >> wsShift;
  int wsm = (1 << wsShift) - 1;
  int tt = ((h & wsm) << wsShift) + (w & wsm);
  return ((((b << 3) | bi) << 3) | bj) * 85 + tokOff + tt;
}

// ---------------- weights: fp32 [K][N] -> bf16 [N][K] ----------------
struct PrepW {
  const float* src[12];
  short* dst[12];
  int kshift[12];
  int N[12];
  int off[13];
};
__global__ __launch_bounds__(256) void prep_w_kernel(PrepW p) {
  int i = blockIdx.x * 256 + threadIdx.x;
  int s = 0;
#pragma unroll
  for (int t = 0; t < 12; t++) if (i >= p.off[t + 1]) s = t + 1;
  if (s >= 12) return;
  int e = i - p.off[s];
  int K = 1 << p.kshift[s];
  int n = e >> p.kshift[s];
  int k = e & (K - 1);
  p.dst[s][e] = (short)f2b(p.src[s][(size_t)k * p.N[s] + n]);
}

// ---------------- fused fc (all 4 levels, f32 input) + partition + LN1 -------
// blocks [0,64): lvl3 split-K; [64,320): lvl2 split-K; [320,576): lvl1;
// [576,1600): lvl0, 1 tile/wave, weights hoisted to registers.
struct FcAllArgs {
  const float* xin[4];
  const short* wt[4];
  const float* bias[4];
  int hsS[4]; int wsS[4]; int tokOff[4]; int chShift[4];
};
__global__ __launch_bounds__(256) void fc_all(
    FcAllArgs A, const float* __restrict__ lng, const float* __restrict__ lnb,
    float* __restrict__ X, short* __restrict__ XB) {
  __shared__ float red[4][16 * 129];
  int bid = blockIdx.x;
  int wv = threadIdx.x >> 6, lane = threadIdx.x & 63;
  int col15 = lane & 15, kg = lane >> 4;

  if (bid >= 576) {
    // ---- lvl0: 1024 blocks x 4 waves, 1 tile of 16 tokens per wave ----
    const float* XIN = A.xin[0];
    const short* Wt = A.wt[0];
    const float* bias = A.bias[0];
    int hsShift = A.hsS[0], wsShift = A.wsS[0], tokOff = A.tokOff[0];
    bf16x8 w[8][4];
#pragma unroll
    for (int nt = 0; nt < 8; nt++)
#pragma unroll
      for (int ks = 0; ks < 4; ks++)
        w[nt][ks] = ldg8(Wt + (size_t)(nt * 16 + col15) * 128 + ks * 32 + kg * 8);
    int t = (bid - 576) * 4 + wv;  // 0..4095
    int p0 = t * 16;
    const float* abase = XIN + (size_t)(p0 + col15) * 128 + kg * 8;
    bf16x8 a[4];
#pragma unroll
    for (int ks = 0; ks < 4; ks++) a[ks] = ldf8(abase + ks * 32);
    f32x4 c[8];
#pragma unroll
    for (int nt = 0; nt < 8; nt++) c[nt] = (f32x4){0.f, 0.f, 0.f, 0.f};
#pragma unroll
    for (int nt = 0; nt < 8; nt++)
#pragma unroll
      for (int ks = 0; ks < 4; ks++)
        c[nt] = MFMA(w[nt][ks], a[ks], c[nt], 0, 0, 0);  // swapped
    float vals[8][4];
#pragma unroll
    for (int nt = 0; nt < 8; nt++) {
      float4 bb = *(const float4*)&bias[nt * 16 + kg * 4];
      vals[nt][0] = c[nt][0] + bb.x; vals[nt][1] = c[nt][1] + bb.y;
      vals[nt][2] = c[nt][2] + bb.z; vals[nt][3] = c[nt][3] + bb.w;
    }
    float s1 = 0.f, s2 = 0.f;
#pragma unroll
    for (int nt = 0; nt < 8; nt++)
#pragma unroll
      for (int r = 0; r < 4; r++) { float v = vals[nt][r]; s1 += v; s2 += v * v; }
    s1 += __shfl_xor(s1, 16); s2 += __shfl_xor(s2, 16);
    s1 += __shfl_xor(s1, 32); s2 += __shfl_xor(s2, 32);
    float mean = s1 * (1.f / 128.f);
    float inv = rsqrtf(s2 * (1.f / 128.f) - mean * mean + 1e-6f);
    size_t row = (size_t)tokmap(p0 + col15, hsShift, wsShift, tokOff) * 128;
#pragma unroll
    for (int nt = 0; nt < 8; nt++) {
      int c0 = nt * 16 + kg * 4;
      float4 g4 = *(const float4*)&lng[c0];
      float4 b4 = *(const float4*)&lnb[c0];
      float4 xs;
      xs.x = vals[nt][0]; xs.y = vals[nt][1]; xs.z = vals[nt][2]; xs.w = vals[nt][3];
      *(float4*)&X[row + c0] = xs;
      *(uint2*)&XB[row + c0] = pk4(
          (vals[nt][0] - mean) * inv * g4.x + b4.x,
          (vals[nt][1] - mean) * inv * g4.y + b4.y,
          (vals[nt][2] - mean) * inv * g4.z + b4.z,
          (vals[nt][3] - mean) * inv * g4.w + b4.w);
    }
    return;
  }

  int lvl, lb;
  if (bid < 64) { lvl = 3; lb = bid; }
  else if (bid < 320) { lvl = 2; lb = bid - 64; }
  else { lvl = 1; lb = bid - 320; }
  const float* XIN = A.xin[lvl];
  const short* Wt = A.wt[lvl];
  const float* bias = A.bias[lvl];
  int CH = 1 << A.chShift[lvl];
  int hsShift = A.hsS[lvl], wsShift = A.wsS[lvl], tokOff = A.tokOff[lvl];

  if (lvl >= 2) {
    // ---- 16-token block, 4-way split-K ----
    int p0 = lb * 16;
    int kb = wv * (CH >> 2);
    const float* abase = XIN + (size_t)(p0 + col15) * CH + kb + kg * 8;
    f32x4 c[8];
#pragma unroll
    for (int nt = 0; nt < 8; nt++) c[nt] = (f32x4){0.f, 0.f, 0.f, 0.f};
    int kiters = CH >> 7;
    for (int ks = 0; ks < kiters; ks++) {
      bf16x8 a = ldf8(abase + ks * 32);
#pragma unroll
      for (int nt = 0; nt < 8; nt++) {
        bf16x8 b = ldg8(Wt + (size_t)(nt * 16 + col15) * CH + kb + ks * 32 + kg * 8);
        c[nt] = MFMA(b, a, c[nt], 0, 0, 0);  // swapped: C[col=token]
      }
    }
    // red[token=col15][col=nt*16+kg*4+r]
#pragma unroll
    for (int nt = 0; nt < 8; nt++)
#pragma unroll
      for (int r = 0; r < 4; r++)
        red[wv][col15 * 129 + nt * 16 + kg * 4 + r] = c[nt][r];
    __syncthreads();
    // finish: wave wv handles tokens wv*4..wv*4+3 (kg selects token)
    int tt = wv * 4 + kg;
    float v[8], gv[8], bv[8];
#pragma unroll
    for (int nt = 0; nt < 8; nt++) {
      int col = nt * 16 + col15;
      v[nt] = red[0][tt * 129 + col] + red[1][tt * 129 + col] +
              red[2][tt * 129 + col] + red[3][tt * 129 + col] + bias[col];
      gv[nt] = lng[col]; bv[nt] = lnb[col];
    }
    float s1 = 0.f, s2 = 0.f;
#pragma unroll
    for (int nt = 0; nt < 8; nt++) { s1 += v[nt]; s2 += v[nt] * v[nt]; }
#pragma unroll
    for (int m = 1; m < 16; m <<= 1) { s1 += __shfl_xor(s1, m); s2 += __shfl_xor(s2, m); }
    float mean = s1 * (1.f / 128.f);
    float inv = rsqrtf(s2 * (1.f / 128.f) - mean * mean + 1e-6f);
    size_t row = (size_t)tokmap(p0 + tt, hsShift, wsShift, tokOff) * 128;
#pragma unroll
    for (int nt = 0; nt < 8; nt++) {
      int col = nt * 16 + col15;
      X[row + col] = v[nt];
      XB[row + col] = (short)f2b((v[nt] - mean) * inv * gv[nt] + bv[nt]);
    }
  } else {
    // ---- lvl1: 64-token block, full K per wave ----
    int p0 = lb * 64 + wv * 16;
    const float* abase = XIN + (size_t)(p0 + col15) * CH + kg * 8;
    f32x4 c[8];
#pragma unroll
    for (int nt = 0; nt < 8; nt++) c[nt] = (f32x4){0.f, 0.f, 0.f, 0.f};
    int kiters = CH >> 5;
    for (int ks = 0; ks < kiters; ks++) {
      bf16x8 a = ldf8(abase + ks * 32);
#pragma unroll
      for (int nt = 0; nt < 8; nt++) {
        bf16x8 b = ldg8(Wt + (size_t)(nt * 16 + col15) * CH + ks * 32 + kg * 8);
        c[nt] = MFMA(b, a, c[nt], 0, 0, 0);  // swapped
      }
    }
    float vals[8][4];
#pragma unroll
    for (int nt = 0; nt < 8; nt++) {
      float4 bb = *(const float4*)&bias[nt * 16 + kg * 4];
#pragma unroll
      for (int r = 0; r < 4; r++) vals[nt][r] = c[nt][r] + ((const float*)&bb)[r];
    }
    float s1 = 0.f, s2 = 0.f;
#pragma unroll
    for (int nt = 0; nt < 8; nt++)
#pragma unroll
      for (int r = 0; r < 4; r++) { float v = vals[nt][r]; s1 += v; s2 += v * v; }
    s1 += __shfl_xor(s1, 16); s2 += __shfl_xor(s2, 16);
    s1 += __shfl_xor(s1, 32); s2 += __shfl_xor(s2, 32);
    float mean = s1 * (1.f / 128.f);
    float inv = rsqrtf(s2 * (1.f / 128.f) - mean * mean + 1e-6f);
    size_t row = (size_t)tokmap(p0 + col15, hsShift, wsShift, tokOff) * 128;
#pragma unroll
    for (int nt = 0; nt < 8; nt++) {
      int c0 = nt * 16 + kg * 4;
      float4 g4 = *(const float4*)&lng[c0];
      float4 b4 = *(const float4*)&lnb[c0];
      float4 xs;
      float n0 = (vals[nt][0] - mean) * inv * g4.x + b4.x;
      float n1 = (vals[nt][1] - mean) * inv * g4.y + b4.y;
      float n2 = (vals[nt][2] - mean) * inv * g4.z + b4.z;
      float n3 = (vals[nt][3] - mean) * inv * g4.w + b4.w;
      xs.x = vals[nt][0]; xs.y = vals[nt][1]; xs.z = vals[nt][2]; xs.w = vals[nt][3];
      *(float4*)&X[row + c0] = xs;
      *(uint2*)&XB[row + c0] = pk4(n0, n1, n2, n3);
    }
  }
}

// ---------------- QKV (K=128, N=384): persistent, swapped ----------------
// QKVH layout: [which(3)][head(8)][NTOK][16]
__global__ __launch_bounds__(256) void qkv_mfma(
    const short* __restrict__ XB, const short* __restrict__ Wt,
    short* __restrict__ QKVH, int ntiles) {
  int wv = threadIdx.x >> 6, lane = threadIdx.x & 63;
  int col15 = lane & 15, kg = lane >> 4;
  bf16x8 w[6][4];
#pragma unroll
  for (int i = 0; i < 6; i++)
#pragma unroll
    for (int ks = 0; ks < 4; ks++)
      w[i][ks] = ldg8(Wt + (size_t)((wv * 6 + i) * 16 + col15) * 128 + ks * 32 + kg * 8);
  for (int t = blockIdx.x; t < ntiles; t += gridDim.x) {
    size_t tok0 = (size_t)t * 32;
    bf16x8 a[2][4];
#pragma unroll
    for (int m = 0; m < 2; m++)
#pragma unroll
      for (int ks = 0; ks < 4; ks++)
        a[m][ks] = ldg8(XB + (tok0 + m * 16 + col15) * 128 + ks * 32 + kg * 8);
    f32x4 acc[6][2];
#pragma unroll
    for (int i = 0; i < 6; i++)
#pragma unroll
      for (int m = 0; m < 2; m++) acc[i][m] = (f32x4){0.f, 0.f, 0.f, 0.f};
#pragma unroll
    for (int i = 0; i < 6; i++)
#pragma unroll
      for (int m = 0; m < 2; m++)
#pragma unroll
        for (int ks = 0; ks < 4; ks++)
          acc[i][m] = MFMA(w[i][ks], a[m][ks], acc[i][m], 0, 0, 0);  // swapped
#pragma unroll
    for (int i = 0; i < 6; i++) {
      size_t hb = (size_t)(wv * 6 + i) * NTOK;
#pragma unroll
      for (int m = 0; m < 2; m++) {
        size_t tok = tok0 + m * 16 + col15;
        *(uint2*)&QKVH[(hb + tok) * 16 + kg * 4] =
            pk4(acc[i][m][0], acc[i][m][1], acc[i][m][2], acc[i][m][3]);
      }
    }
  }
}

// ---------------- MFMA attention, 32x32x16 swapped-operand form --------------
#define PLD 104
__global__ __launch_bounds__(64) void attn_mfma(
    const short* __restrict__ QKVH, short* __restrict__ ATB) {
  int blk = blockIdx.x;
  int h = blk & 7, sb = blk >> 3;
  size_t tok0 = (size_t)sb * 85;
  __shared__ short vT[16 * PLD];  // V^T [d][tok], zero-padded to 96
  __shared__ short oT[32 * 24];   // O^T bounce [q][d], row stride 24 elems
  int lane = threadIdx.x;
  int c31 = lane & 31, hh = lane >> 5;
  const short* Qp = QKVH + (size_t)h * NTOK * 16;
  const short* Kp = QKVH + (size_t)(8 + h) * NTOK * 16;
  const short* Vp = QKVH + (size_t)(16 + h) * NTOK * 16;

#pragma unroll
  for (int i = 0; i < 3; i++) {
    int idx = i * 64 + lane;
    if (idx < 170) {
      int m = idx >> 1, half = (idx & 1) << 3;
      bf16x8 v = ldg8(Vp + (tok0 + m) * 16 + half);
#pragma unroll
      for (int j = 0; j < 8; j++) vT[(half + j) * PLD + m] = v[j];
    }
  }
  for (int i = lane; i < 176; i += 64) {
    int d = i / 11, m = 85 + i % 11;
    vT[d * PLD + m] = 0;
  }

  bf16x8 ka[3];
#pragma unroll
  for (int kt = 0; kt < 3; kt++) {
    int tk = kt * 32 + c31; if (tk > 84) tk = 84;
    ka[kt] = ldg8(Kp + (tok0 + tk) * 16 + hh * 8);
  }
  bf16x8 va[6];
  int dm = lane & 15;
#pragma unroll
  for (int ks = 0; ks < 6; ks++)
    va[ks] = *(const bf16x8*)&vT[dm * PLD + ks * 16 + hh * 8];

#pragma unroll
  for (int qt = 0; qt < 3; qt++) {
    int tq = qt * 32 + c31; if (tq > 84) tq = 84;
    bf16x8 qb = ldg8(Qp + (tok0 + tq) * 16 + hh * 8);
    f32x16 s[3];
#pragma unroll
    for (int kt = 0; kt < 3; kt++) s[kt] = zero16();
#pragma unroll
    for (int kt = 0; kt < 3; kt++) s[kt] = MFMA32(ka[kt], qb, s[kt], 0, 0, 0);
#pragma unroll
    for (int r = 0; r < 16; r++) {
      int krow = 64 + (r & 3) + 8 * (r >> 2) + 4 * hh;
      if (krow > 84) s[2][r] = -3e30f;
    }
    float mx = -3e30f;
#pragma unroll
    for (int kt = 0; kt < 3; kt++)
#pragma unroll
      for (int r = 0; r < 16; r++) mx = fmaxf(mx, s[kt][r]);
    mx = fmaxf(mx, __shfl_xor(mx, 32));
    float sum = 0.f;
#pragma unroll
    for (int kt = 0; kt < 3; kt++)
#pragma unroll
      for (int r = 0; r < 16; r++) { float e = __expf(s[kt][r] - mx); s[kt][r] = e; sum += e; }
    sum += __shfl_xor(sum, 32);
    float inv = 1.f / sum;
    bf16x8 pb[6];
#pragma unroll
    for (int ks = 0; ks < 6; ks++) {
      int kt = ks >> 1;
      int b = 8 * (ks & 1);
      unsigned int u0 = pk2(s[kt][b + 0] * inv, s[kt][b + 1] * inv);
      unsigned int u1 = pk2(s[kt][b + 2] * inv, s[kt][b + 3] * inv);
      unsigned int v0 = pk2(s[kt][b + 4] * inv, s[kt][b + 5] * inv);
      unsigned int v1 = pk2(s[kt][b + 6] * inv, s[kt][b + 7] * inv);
      unsigned int u0x = (unsigned int)__shfl_xor((int)u0, 32);
      unsigned int u1x = (unsigned int)__shfl_xor((int)u1, 32);
      unsigned int v0x = (unsigned int)__shfl_xor((int)v0, 32);
      unsigned int v1x = (unsigned int)__shfl_xor((int)v1, 32);
      unsigned int wv[4];
      wv[0] = hh ? v0x : u0;
      wv[1] = hh ? v1x : u1;
      wv[2] = hh ? v0 : u0x;
      wv[3] = hh ? v1 : u1x;
      __builtin_memcpy(&pb[ks], wv, 16);
    }
    f32x16 o = zero16();
#pragma unroll
    for (int ks = 0; ks < 6; ks++) o = MFMA32(va[ks], pb[ks], o, 0, 0, 0);
#pragma unroll
    for (int r = 0; r < 8; r++) {
      int d = (r & 3) + 8 * (r >> 2) + 4 * hh;
      oT[c31 * 24 + d] = (short)f2b(o[r]);
    }
    int tl = lane >> 1, hf = (lane & 1) * 8;
    int tq2 = qt * 32 + tl;
    if (tq2 < 85) {
      bf16x8 ov = *(const bf16x8*)&oT[tl * 24 + hf];
      *(bf16x8*)&ATB[(tok0 + tq2) * 128 + h * 16 + hf] = ov;
    }
  }
}

// ---------------- proj (K=128, N=128) + residual + fused LN2, swapped --------
__global__ __launch_bounds__(256) void proj_mfma(
    const short* __restrict__ ATB, const short* __restrict__ Wt,
    const float* __restrict__ lng, const float* __restrict__ lnb,
    float* __restrict__ X, short* __restrict__ XB) {
  int wid = threadIdx.x >> 6, lane = threadIdx.x & 63;
  int col15 = lane & 15, kg = lane >> 4;
  size_t tok0 = (size_t)blockIdx.x * 64 + wid * 16;
  const short* abase = ATB + (tok0 + col15) * 128 + kg * 8;
  bf16x8 a[4];
#pragma unroll
  for (int ks = 0; ks < 4; ks++) a[ks] = ldg8(abase + ks * 32);
  size_t row = (tok0 + col15) * 128;
  float vals[8][4];
#pragma unroll
  for (int nt = 0; nt < 8; nt++) {
    const short* bbase = Wt + (size_t)(nt * 16 + col15) * 128 + kg * 8;
    f32x4 acc = (f32x4){0.f, 0.f, 0.f, 0.f};
#pragma unroll
    for (int ks = 0; ks < 4; ks++) acc = MFMA(ldg8(bbase + ks * 32), a[ks], acc, 0, 0, 0);
    float4 xr = *(const float4*)&X[row + nt * 16 + kg * 4];
    vals[nt][0] = acc[0] + xr.x; vals[nt][1] = acc[1] + xr.y;
    vals[nt][2] = acc[2] + xr.z; vals[nt][3] = acc[3] + xr.w;
  }
  float s1 = 0.f, s2 = 0.f;
#pragma unroll
  for (int nt = 0; nt < 8; nt++)
#pragma unroll
    for (int r = 0; r < 4; r++) { float v = vals[nt][r]; s1 += v; s2 += v * v; }
  s1 += __shfl_xor(s1, 16); s2 += __shfl_xor(s2, 16);
  s1 += __shfl_xor(s1, 32); s2 += __shfl_xor(s2, 32);
  float mean = s1 * (1.f / 128.f);
  float inv = rsqrtf(s2 * (1.f / 128.f) - mean * mean + 1e-6f);
#pragma unroll
  for (int nt = 0; nt < 8; nt++) {
    int c0 = nt * 16 + kg * 4;
    float4 g4 = *(const float4*)&lng[c0];
    float4 b4 = *(const float4*)&lnb[c0];
    float4 xs;
    xs.x = vals[nt][0]; xs.y = vals[nt][1]; xs.z = vals[nt][2]; xs.w = vals[nt][3];
    *(float4*)&X[row + c0] = xs;
    *(uint2*)&XB[row + c0] = pk4(
        (vals[nt][0] - mean) * inv * g4.x + b4.x,
        (vals[nt][1] - mean) * inv * g4.y + b4.y,
        (vals[nt][2] - mean) * inv * g4.z + b4.z,
        (vals[nt][3] - mean) * inv * g4.w + b4.w);
  }
}

// ---------------- fused MLP: XB = bf16(relu(XB@W1+b1)@W2 + b2 + X) ----------
// 4 waves / 256 thr; ONE 32-token tile per block (grid 2720); one barrier.
// stage1: wave wv computes H cols [wv*128,+128) (W1 streamed from L2);
// stage2: wave wv computes out cols [wv*32,+32) (W2 streamed; each H read
// feeds 2 MFMAs). H in LDS [32][520] bf16 (pad-520 = proven r11 layout).
#define HLD 520
__global__ __launch_bounds__(256) void ffu_mfma(
    const short* __restrict__ XB, const short* __restrict__ W1t,
    const float* __restrict__ b1, const short* __restrict__ W2t,
    const float* __restrict__ b2, const float* __restrict__ X,
    short* __restrict__ XBo) {
  __shared__ short Hs[32 * HLD];
  int wv = threadIdx.x >> 6, lane = threadIdx.x & 63;
  int col15 = lane & 15, kg = lane >> 4;
  size_t tok0 = (size_t)blockIdx.x * 32;
  bf16x8 a[2][4];
#pragma unroll
  for (int m = 0; m < 2; m++)
#pragma unroll
    for (int ks = 0; ks < 4; ks++)
      a[m][ks] = ldg8(XB + (tok0 + m * 16 + col15) * 128 + ks * 32 + kg * 8);
  // stage 1: H cols [wv*128, wv*128+128)
  f32x4 acc1[8][2];
#pragma unroll
  for (int nt = 0; nt < 8; nt++)
#pragma unroll
    for (int m = 0; m < 2; m++) acc1[nt][m] = (f32x4){0.f, 0.f, 0.f, 0.f};
#pragma unroll
  for (int nt = 0; nt < 8; nt++)
#pragma unroll
    for (int ks = 0; ks < 4; ks++) {
      bf16x8 w1f = ldg8(W1t + (size_t)(wv * 128 + nt * 16 + col15) * 128 + ks * 32 + kg * 8);
#pragma unroll
      for (int m = 0; m < 2; m++)
        acc1[nt][m] = MFMA(w1f, a[m][ks], acc1[nt][m], 0, 0, 0);
    }
#pragma unroll
  for (int nt = 0; nt < 8; nt++) {
    int c0 = wv * 128 + nt * 16 + kg * 4;
    float4 b1v = *(const float4*)&b1[c0];
#pragma unroll
    for (int m = 0; m < 2; m++) {
      int hrow = m * 16 + col15;
      *(uint2*)&Hs[hrow * HLD + c0] = pk4(
          fmaxf(acc1[nt][m][0] + b1v.x, 0.f), fmaxf(acc1[nt][m][1] + b1v.y, 0.f),
          fmaxf(acc1[nt][m][2] + b1v.z, 0.f), fmaxf(acc1[nt][m][3] + b1v.w, 0.f));
    }
  }
  __syncthreads();
  // stage 2: out cols [wv*32, wv*32+32); each H read feeds 2 MFMAs
  f32x4 acc2[2][2];
#pragma unroll
  for (int i = 0; i < 2; i++)
#pragma unroll
    for (int m = 0; m < 2; m++) acc2[i][m] = (f32x4){0.f, 0.f, 0.f, 0.f};
#pragma unroll
  for (int ks = 0; ks < 16; ks++) {
    bf16x8 w2f[2];
#pragma unroll
    for (int i = 0; i < 2; i++)
      w2f[i] = ldg8(W2t + (size_t)(wv * 32 + i * 16 + col15) * 512 + ks * 32 + kg * 8);
#pragma unroll
    for (int m = 0; m < 2; m++) {
      bf16x8 hhf = *(const bf16x8*)&Hs[(m * 16 + col15) * HLD + ks * 32 + kg * 8];
#pragma unroll
      for (int i = 0; i < 2; i++)
        acc2[i][m] = MFMA(w2f[i], hhf, acc2[i][m], 0, 0, 0);
    }
  }
#pragma unroll
  for (int i = 0; i < 2; i++) {
    int c0 = wv * 32 + i * 16 + kg * 4;
    float4 b2v = *(const float4*)&b2[c0];
#pragma unroll
    for (int m = 0; m < 2; m++) {
      size_t row = (tok0 + m * 16 + col15) * 128;
      float4 xr = *(const float4*)&X[row + c0];
      *(uint2*)&XBo[row + c0] = pk4(
          xr.x + acc2[i][m][0] + b2v.x, xr.y + acc2[i][m][1] + b2v.y,
          xr.z + acc2[i][m][2] + b2v.z, xr.w + acc2[i][m][3] + b2v.w);
    }
  }
}

// ---------------- fused un-partition + reverse projection, swapped -----------
struct RevArgs {
  const short* wt[4];
  const float* bias[4];
  float* out[4];
  int hsS[4]; int wsS[4]; int tokOff[4];
  int chShift[4];   // log2 CHout
  int ntcShift[4];  // log2(CHout/32)
};
__global__ __launch_bounds__(256) void rev_all(RevArgs A, const short* __restrict__ XB) {
  int g = blockIdx.x * 4 + (threadIdx.x >> 6);
  int lane = threadIdx.x & 63, col15 = lane & 15, kg = lane >> 4;
  int lvl, lb;
  if (g < 2048) { lvl = 3; lb = g; }
  else if (g < 6144) { lvl = 2; lb = g - 2048; }
  else if (g < 14336) { lvl = 1; lb = g - 6144; }
  else { lvl = 0; lb = g - 14336; }
  int ntcS = A.ntcShift[lvl];
  int tr = lb >> ntcS, tc = lb & ((1 << ntcS) - 1);
  int CHout = 1 << A.chShift[lvl];
  int p0 = tr * 16, c0 = tc * 32;
  int atok = tokmap(p0 + col15, A.hsS[lvl], A.wsS[lvl], A.tokOff[lvl]);
  const short* abase = XB + (size_t)atok * 128 + kg * 8;
  bf16x8 a[4];
#pragma unroll
  for (int ks = 0; ks < 4; ks++) a[ks] = ldg8(abase + ks * 32);
  const short* Wt = A.wt[lvl];
  const float* bias = A.bias[lvl];
  float* out = A.out[lvl];
  size_t orow = (size_t)(p0 + col15) * CHout;
#pragma unroll
  for (int i = 0; i < 2; i++) {
    int col = c0 + i * 16 + col15;
    const short* bbase = Wt + (size_t)col * 128 + kg * 8;
    f32x4 c = (f32x4){0.f, 0.f, 0.f, 0.f};
#pragma unroll
    for (int ks = 0; ks < 4; ks++) c = MFMA(ldg8(bbase + ks * 32), a[ks], c, 0, 0, 0);
    int cc = c0 + i * 16 + kg * 4;
    float4 b4 = *(const float4*)&bias[cc];
    float4 o;
    o.x = c[0] + b4.x; o.y = c[1] + b4.y; o.z = c[2] + b4.z; o.w = c[3] + b4.w;
    *(float4*)&out[orow + cc] = o;
  }
}

extern "C" void kernel_launch(void* const* d_in, const int* in_sizes, int n_in,
                              void* d_out, int out_size, void* d_ws, size_t ws_size,
                              hipStream_t stream) {
  const float* x[4]; const float* fcW[4]; const float* fcb[4];
  const float* revW[4]; const float* revb[4];
  for (int j = 0; j < 4; j++) {
    x[j]    = (const float*)d_in[j * 5 + 0];
    fcW[j]  = (const float*)d_in[j * 5 + 1];
    fcb[j]  = (const float*)d_in[j * 5 + 2];
    revW[j] = (const float*)d_in[j * 5 + 3];
    revb[j] = (const float*)d_in[j * 5 + 4];
  }
  const float* ln1g = (const float*)d_in[20];
  const float* ln1b = (const float*)d_in[21];
  const float* ln2g = (const float*)d_in[22];
  const float* ln2b = (const float*)d_in[23];
  const float* qkvW = (const float*)d_in[24];
  const float* projW = (const float*)d_in[25];
  const float* fc1W = (const float*)d_in[26];
  const float* fc1b = (const float*)d_in[27];
  const float* fc2W = (const float*)d_in[28];
  const float* fc2b = (const float*)d_in[29];

  // workspace layout
  float* X    = (float*)d_ws;                           // NTOK*128 f32
  short* QKVH = (short*)(X + (size_t)NTOK * 128);       // NTOK*384 bf16 (head-major)
  short* XB   = QKVH + (size_t)NTOK * 384;              // NTOK*128 bf16
  short* ATB  = XB + (size_t)NTOK * 128;                // NTOK*128 bf16
  short* XIN  = ATB + (size_t)NTOK * 128;               // scratch
  short* WT   = XIN + (size_t)15728640;                 // 688128 bf16

  static const int CH[4] = {128, 256, 512, 1024};
  static const int hsS[4] = {6, 5, 4, 3};
  static const int wsS[4] = {3, 2, 1, 0};
  static const int tokOff[4] = {0, 64, 80, 84};
  static const int chShift[4] = {7, 8, 9, 10};
  static const int fcWtOff[4] = {0, 16384, 49152, 114688};
  static const int revWtOff[4] = {245760, 262144, 294912, 360448};
  const int qkvWtOff = 491520, projWtOff = 540672, fc1WtOff = 557056, fc2WtOff = 622592;

  PrepW pw;
  int cum = 0;
  auto setw = [&](int idx, const float* src, short* dst, int K, int N) {
    pw.src[idx] = src; pw.dst[idx] = dst;
    int ksh = 0; while ((1 << ksh) < K) ksh++;
    pw.kshift[idx] = ksh; pw.N[idx] = N;
    pw.off[idx] = cum; cum += K * N;
  };
  for (int j = 0; j < 4; j++) setw(j, fcW[j], WT + fcWtOff[j], CH[j], 128);
  for (int j = 0; j < 4; j++) setw(4 + j, revW[j], WT + revWtOff[j], 128, CH[j]);
  setw(8, qkvW, WT + qkvWtOff, 128, 384);
  setw(9, projW, WT + projWtOff, 128, 128);
  setw(10, fc1W, WT + fc1WtOff, 128, 512);
  setw(11, fc2W, WT + fc2WtOff, 512, 128);
  pw.off[12] = cum;
  prep_w_kernel<<<2688, 256, 0, stream>>>(pw);

  // fused fc: [L3:64][L2:256][L1:256][L0:1024] = 1600 blocks
  FcAllArgs fa;
  for (int j = 0; j < 4; j++) {
    fa.xin[j] = x[j];
    fa.wt[j] = WT + fcWtOff[j];
    fa.bias[j] = fcb[j];
    fa.hsS[j] = hsS[j]; fa.wsS[j] = wsS[j];
    fa.tokOff[j] = tokOff[j]; fa.chShift[j] = chShift[j];
  }
  fc_all<<<1600, 256, 0, stream>>>(fa, ln1g, ln1b, X, XB);

  qkv_mfma<<<1024, 256, 0, stream>>>(XB, WT + qkvWtOff, QKVH, NTOK / 32);
  attn_mfma<<<1024 * 8, 64, 0, stream>>>(QKVH, ATB);
  proj_mfma<<<NTOK / 64, 256, 0, stream>>>(ATB, WT + projWtOff, ln2g, ln2b, X, XB);
  // fused MLP, single dispatch; one 32-token tile per block, one barrier
  ffu_mfma<<<NTOK / 32, 256, 0, stream>>>(XB, WT + fc1WtOff, fc1b, WT + fc2WtOff, fc2b, X, XB);

  // fused rev: 30720 wave-tiles (L3 first), 4 per block
  RevArgs ra;
  float* out = (float*)d_out;
  static const size_t outOffArr[4] = {0, 8388608, 12582912, 14680064};
  static const int ntcShift[4] = {2, 3, 4, 5};
  for (int j = 0; j < 4; j++) {
    ra.wt[j] = WT + revWtOff[j];
    ra.bias[j] = revb[j];
    ra.out[j] = out + outOffArr[j];
    ra.hsS[j] = hsS[j]; ra.wsS[j] = wsS[j]; ra.tokOff[j] = tokOff[j];
    ra.chShift[j] = chShift[j]; ra.ntcShift[j] = ntcShift[j];
  }
  rev_all<<<7680, 256, 0, stream>>>(ra, XB);
}

// Round 14
// 285.682 us; speedup vs baseline: 1.1313x; 1.1313x over previous
//
#include <hip/hip_runtime.h>
#include <hip/hip_bf16.h>

#define NTOK 87040  // 1024 windows * 85 tokens

typedef __attribute__((ext_vector_type(8))) short bf16x8;
typedef __attribute__((ext_vector_type(4))) float f32x4;
typedef __attribute__((ext_vector_type(16))) float f32x16;

#define MFMA __builtin_amdgcn_mfma_f32_16x16x32_bf16
#define MFMA32 __builtin_amdgcn_mfma_f32_32x32x16_bf16

__device__ __forceinline__ unsigned short f2b(float f) {
  unsigned int u; __builtin_memcpy(&u, &f, 4);
  u += 0x7fffu + ((u >> 16) & 1u);  // RNE
  return (unsigned short)(u >> 16);
}
__device__ __forceinline__ float b2f(short s) {
  unsigned int u = ((unsigned int)(unsigned short)s) << 16;
  float f; __builtin_memcpy(&f, &u, 4);
  return f;
}
__device__ __forceinline__ bf16x8 ldg8(const short* p) { return *(const bf16x8*)p; }
__device__ __forceinline__ f32x16 zero16() {
  f32x16 z;
#pragma unroll
  for (int i = 0; i < 16; i++) z[i] = 0.f;
  return z;
}
__device__ __forceinline__ unsigned int pk2(float lo, float hi) {
  float2 t2; t2.x = lo; t2.y = hi;
  __hip_bfloat162 t = __float22bfloat162_rn(t2);
  unsigned int r; __builtin_memcpy(&r, &t, 4);
  return r;
}
__device__ __forceinline__ uint2 pk4(float a, float b, float c, float d) {
  uint2 r; r.x = pk2(a, b); r.y = pk2(c, d);
  return r;
}
// load 8 f32, convert to bf16x8 fragment (RNE, same as prep path)
__device__ __forceinline__ bf16x8 ldf8(const float* p) {
  float4 a = *(const float4*)p;
  float4 b = *(const float4*)(p + 4);
  unsigned int w[4] = {pk2(a.x, a.y), pk2(a.z, a.w), pk2(b.x, b.y), pk2(b.z, b.w)};
  bf16x8 o; __builtin_memcpy(&o, w, 16);
  return o;
}

// natural spatial row p -> window token index
__device__ __forceinline__ int tokmap(int p, int hsShift, int wsShift, int tokOff) {
  int HSm = (1 << hsShift) - 1;
  int w = p & HSm;
  int h = (p >> hsShift) & HSm;
  int b = p >> (2 * hsShift);
  int bi = h >> wsShift, bj = w >> wsShift;
  int wsm = (1 << wsShift) - 1;
  int tt = ((h & wsm) << wsShift) + (w & wsm);
  return ((((b << 3) | bi) << 3) | bj) * 85 + tokOff + tt;
}

// ---------------- weights: fp32 [K][N] -> bf16 [N][K] ----------------
struct PrepW {
  const float* src[12];
  short* dst[12];
  int kshift[12];
  int N[12];
  int off[13];
};
__global__ __launch_bounds__(256) void prep_w_kernel(PrepW p) {
  int i = blockIdx.x * 256 + threadIdx.x;
  int s = 0;
#pragma unroll
  for (int t = 0; t < 12; t++) if (i >= p.off[t + 1]) s = t + 1;
  if (s >= 12) return;
  int e = i - p.off[s];
  int K = 1 << p.kshift[s];
  int n = e >> p.kshift[s];
  int k = e & (K - 1);
  p.dst[s][e] = (short)f2b(p.src[s][(size_t)k * p.N[s] + n]);
}

// ---------------- fused fc (all 4 levels, f32 input) + partition + LN1 -------
// blocks [0,64): lvl3 split-K; [64,320): lvl2 split-K; [320,576): lvl1;
// [576,1600): lvl0, 1 tile/wave, weights hoisted to registers.
struct FcAllArgs {
  const float* xin[4];
  const short* wt[4];
  const float* bias[4];
  int hsS[4]; int wsS[4]; int tokOff[4]; int chShift[4];
};
__global__ __launch_bounds__(256) void fc_all(
    FcAllArgs A, const float* __restrict__ lng, const float* __restrict__ lnb,
    float* __restrict__ X, short* __restrict__ XB) {
  __shared__ float red[4][16 * 129];
  int bid = blockIdx.x;
  int wv = threadIdx.x >> 6, lane = threadIdx.x & 63;
  int col15 = lane & 15, kg = lane >> 4;

  if (bid >= 576) {
    // ---- lvl0: 1024 blocks x 4 waves, 1 tile of 16 tokens per wave ----
    const float* XIN = A.xin[0];
    const short* Wt = A.wt[0];
    const float* bias = A.bias[0];
    int hsShift = A.hsS[0], wsShift = A.wsS[0], tokOff = A.tokOff[0];
    bf16x8 w[8][4];
#pragma unroll
    for (int nt = 0; nt < 8; nt++)
#pragma unroll
      for (int ks = 0; ks < 4; ks++)
        w[nt][ks] = ldg8(Wt + (size_t)(nt * 16 + col15) * 128 + ks * 32 + kg * 8);
    int t = (bid - 576) * 4 + wv;  // 0..4095
    int p0 = t * 16;
    const float* abase = XIN + (size_t)(p0 + col15) * 128 + kg * 8;
    bf16x8 a[4];
#pragma unroll
    for (int ks = 0; ks < 4; ks++) a[ks] = ldf8(abase + ks * 32);
    f32x4 c[8];
#pragma unroll
    for (int nt = 0; nt < 8; nt++) c[nt] = (f32x4){0.f, 0.f, 0.f, 0.f};
#pragma unroll
    for (int nt = 0; nt < 8; nt++)
#pragma unroll
      for (int ks = 0; ks < 4; ks++)
        c[nt] = MFMA(w[nt][ks], a[ks], c[nt], 0, 0, 0);  // swapped
    float vals[8][4];
#pragma unroll
    for (int nt = 0; nt < 8; nt++) {
      float4 bb = *(const float4*)&bias[nt * 16 + kg * 4];
      vals[nt][0] = c[nt][0] + bb.x; vals[nt][1] = c[nt][1] + bb.y;
      vals[nt][2] = c[nt][2] + bb.z; vals[nt][3] = c[nt][3] + bb.w;
    }
    float s1 = 0.f, s2 = 0.f;
#pragma unroll
    for (int nt = 0; nt < 8; nt++)
#pragma unroll
      for (int r = 0; r < 4; r++) { float v = vals[nt][r]; s1 += v; s2 += v * v; }
    s1 += __shfl_xor(s1, 16); s2 += __shfl_xor(s2, 16);
    s1 += __shfl_xor(s1, 32); s2 += __shfl_xor(s2, 32);
    float mean = s1 * (1.f / 128.f);
    float inv = rsqrtf(s2 * (1.f / 128.f) - mean * mean + 1e-6f);
    size_t row = (size_t)tokmap(p0 + col15, hsShift, wsShift, tokOff) * 128;
#pragma unroll
    for (int nt = 0; nt < 8; nt++) {
      int c0 = nt * 16 + kg * 4;
      float4 g4 = *(const float4*)&lng[c0];
      float4 b4 = *(const float4*)&lnb[c0];
      float4 xs;
      xs.x = vals[nt][0]; xs.y = vals[nt][1]; xs.z = vals[nt][2]; xs.w = vals[nt][3];
      *(float4*)&X[row + c0] = xs;
      *(uint2*)&XB[row + c0] = pk4(
          (vals[nt][0] - mean) * inv * g4.x + b4.x,
          (vals[nt][1] - mean) * inv * g4.y + b4.y,
          (vals[nt][2] - mean) * inv * g4.z + b4.z,
          (vals[nt][3] - mean) * inv * g4.w + b4.w);
    }
    return;
  }

  int lvl, lb;
  if (bid < 64) { lvl = 3; lb = bid; }
  else if (bid < 320) { lvl = 2; lb = bid - 64; }
  else { lvl = 1; lb = bid - 320; }
  const float* XIN = A.xin[lvl];
  const short* Wt = A.wt[lvl];
  const float* bias = A.bias[lvl];
  int CH = 1 << A.chShift[lvl];
  int hsShift = A.hsS[lvl], wsShift = A.wsS[lvl], tokOff = A.tokOff[lvl];

  if (lvl >= 2) {
    // ---- 16-token block, 4-way split-K ----
    int p0 = lb * 16;
    int kb = wv * (CH >> 2);
    const float* abase = XIN + (size_t)(p0 + col15) * CH + kb + kg * 8;
    f32x4 c[8];
#pragma unroll
    for (int nt = 0; nt < 8; nt++) c[nt] = (f32x4){0.f, 0.f, 0.f, 0.f};
    int kiters = CH >> 7;
    for (int ks = 0; ks < kiters; ks++) {
      bf16x8 a = ldf8(abase + ks * 32);
#pragma unroll
      for (int nt = 0; nt < 8; nt++) {
        bf16x8 b = ldg8(Wt + (size_t)(nt * 16 + col15) * CH + kb + ks * 32 + kg * 8);
        c[nt] = MFMA(b, a, c[nt], 0, 0, 0);  // swapped: C[col=token]
      }
    }
    // red[token=col15][col=nt*16+kg*4+r]
#pragma unroll
    for (int nt = 0; nt < 8; nt++)
#pragma unroll
      for (int r = 0; r < 4; r++)
        red[wv][col15 * 129 + nt * 16 + kg * 4 + r] = c[nt][r];
    __syncthreads();
    // finish: wave wv handles tokens wv*4..wv*4+3 (kg selects token)
    int tt = wv * 4 + kg;
    float v[8], gv[8], bv[8];
#pragma unroll
    for (int nt = 0; nt < 8; nt++) {
      int col = nt * 16 + col15;
      v[nt] = red[0][tt * 129 + col] + red[1][tt * 129 + col] +
              red[2][tt * 129 + col] + red[3][tt * 129 + col] + bias[col];
      gv[nt] = lng[col]; bv[nt] = lnb[col];
    }
    float s1 = 0.f, s2 = 0.f;
#pragma unroll
    for (int nt = 0; nt < 8; nt++) { s1 += v[nt]; s2 += v[nt] * v[nt]; }
#pragma unroll
    for (int m = 1; m < 16; m <<= 1) { s1 += __shfl_xor(s1, m); s2 += __shfl_xor(s2, m); }
    float mean = s1 * (1.f / 128.f);
    float inv = rsqrtf(s2 * (1.f / 128.f) - mean * mean + 1e-6f);
    size_t row = (size_t)tokmap(p0 + tt, hsShift, wsShift, tokOff) * 128;
#pragma unroll
    for (int nt = 0; nt < 8; nt++) {
      int col = nt * 16 + col15;
      X[row + col] = v[nt];
      XB[row + col] = (short)f2b((v[nt] - mean) * inv * gv[nt] + bv[nt]);
    }
  } else {
    // ---- lvl1: 64-token block, full K per wave ----
    int p0 = lb * 64 + wv * 16;
    const float* abase = XIN + (size_t)(p0 + col15) * CH + kg * 8;
    f32x4 c[8];
#pragma unroll
    for (int nt = 0; nt < 8; nt++) c[nt] = (f32x4){0.f, 0.f, 0.f, 0.f};
    int kiters = CH >> 5;
    for (int ks = 0; ks < kiters; ks++) {
      bf16x8 a = ldf8(abase + ks * 32);
#pragma unroll
      for (int nt = 0; nt < 8; nt++) {
        bf16x8 b = ldg8(Wt + (size_t)(nt * 16 + col15) * CH + ks * 32 + kg * 8);
        c[nt] = MFMA(b, a, c[nt], 0, 0, 0);  // swapped
      }
    }
    float vals[8][4];
#pragma unroll
    for (int nt = 0; nt < 8; nt++) {
      float4 bb = *(const float4*)&bias[nt * 16 + kg * 4];
#pragma unroll
      for (int r = 0; r < 4; r++) vals[nt][r] = c[nt][r] + ((const float*)&bb)[r];
    }
    float s1 = 0.f, s2 = 0.f;
#pragma unroll
    for (int nt = 0; nt < 8; nt++)
#pragma unroll
      for (int r = 0; r < 4; r++) { float v = vals[nt][r]; s1 += v; s2 += v * v; }
    s1 += __shfl_xor(s1, 16); s2 += __shfl_xor(s2, 16);
    s1 += __shfl_xor(s1, 32); s2 += __shfl_xor(s2, 32);
    float mean = s1 * (1.f / 128.f);
    float inv = rsqrtf(s2 * (1.f / 128.f) - mean * mean + 1e-6f);
    size_t row = (size_t)tokmap(p0 + col15, hsShift, wsShift, tokOff) * 128;
#pragma unroll
    for (int nt = 0; nt < 8; nt++) {
      int c0 = nt * 16 + kg * 4;
      float4 g4 = *(const float4*)&lng[c0];
      float4 b4 = *(const float4*)&lnb[c0];
      float4 xs;
      float n0 = (vals[nt][0] - mean) * inv * g4.x + b4.x;
      float n1 = (vals[nt][1] - mean) * inv * g4.y + b4.y;
      float n2 = (vals[nt][2] - mean) * inv * g4.z + b4.z;
      float n3 = (vals[nt][3] - mean) * inv * g4.w + b4.w;
      xs.x = vals[nt][0]; xs.y = vals[nt][1]; xs.z = vals[nt][2]; xs.w = vals[nt][3];
      *(float4*)&X[row + c0] = xs;
      *(uint2*)&XB[row + c0] = pk4(n0, n1, n2, n3);
    }
  }
}

// ---------------- QKV (K=128, N=384): persistent, swapped ----------------
// QKVH layout: [which(3)][head(8)][NTOK][16]
__global__ __launch_bounds__(256) void qkv_mfma(
    const short* __restrict__ XB, const short* __restrict__ Wt,
    short* __restrict__ QKVH, int ntiles) {
  int wv = threadIdx.x >> 6, lane = threadIdx.x & 63;
  int col15 = lane & 15, kg = lane >> 4;
  bf16x8 w[6][4];
#pragma unroll
  for (int i = 0; i < 6; i++)
#pragma unroll
    for (int ks = 0; ks < 4; ks++)
      w[i][ks] = ldg8(Wt + (size_t)((wv * 6 + i) * 16 + col15) * 128 + ks * 32 + kg * 8);
  for (int t = blockIdx.x; t < ntiles; t += gridDim.x) {
    size_t tok0 = (size_t)t * 32;
    bf16x8 a[2][4];
#pragma unroll
    for (int m = 0; m < 2; m++)
#pragma unroll
      for (int ks = 0; ks < 4; ks++)
        a[m][ks] = ldg8(XB + (tok0 + m * 16 + col15) * 128 + ks * 32 + kg * 8);
    f32x4 acc[6][2];
#pragma unroll
    for (int i = 0; i < 6; i++)
#pragma unroll
      for (int m = 0; m < 2; m++) acc[i][m] = (f32x4){0.f, 0.f, 0.f, 0.f};
#pragma unroll
    for (int i = 0; i < 6; i++)
#pragma unroll
      for (int m = 0; m < 2; m++)
#pragma unroll
        for (int ks = 0; ks < 4; ks++)
          acc[i][m] = MFMA(w[i][ks], a[m][ks], acc[i][m], 0, 0, 0);  // swapped
#pragma unroll
    for (int i = 0; i < 6; i++) {
      size_t hb = (size_t)(wv * 6 + i) * NTOK;
#pragma unroll
      for (int m = 0; m < 2; m++) {
        size_t tok = tok0 + m * 16 + col15;
        *(uint2*)&QKVH[(hb + tok) * 16 + kg * 4] =
            pk4(acc[i][m][0], acc[i][m][1], acc[i][m][2], acc[i][m][3]);
      }
    }
  }
}

// ---------------- MFMA attention, 32x32x16 swapped-operand form --------------
#define PLD 104
__global__ __launch_bounds__(64) void attn_mfma(
    const short* __restrict__ QKVH, short* __restrict__ ATB) {
  int blk = blockIdx.x;
  int h = blk & 7, sb = blk >> 3;
  size_t tok0 = (size_t)sb * 85;
  __shared__ short vT[16 * PLD];  // V^T [d][tok], zero-padded to 96
  __shared__ short oT[32 * 24];   // O^T bounce [q][d], row stride 24 elems
  int lane = threadIdx.x;
  int c31 = lane & 31, hh = lane >> 5;
  const short* Qp = QKVH + (size_t)h * NTOK * 16;
  const short* Kp = QKVH + (size_t)(8 + h) * NTOK * 16;
  const short* Vp = QKVH + (size_t)(16 + h) * NTOK * 16;

#pragma unroll
  for (int i = 0; i < 3; i++) {
    int idx = i * 64 + lane;
    if (idx < 170) {
      int m = idx >> 1, half = (idx & 1) << 3;
      bf16x8 v = ldg8(Vp + (tok0 + m) * 16 + half);
#pragma unroll
      for (int j = 0; j < 8; j++) vT[(half + j) * PLD + m] = v[j];
    }
  }
  for (int i = lane; i < 176; i += 64) {
    int d = i / 11, m = 85 + i % 11;
    vT[d * PLD + m] = 0;
  }

  bf16x8 ka[3];
#pragma unroll
  for (int kt = 0; kt < 3; kt++) {
    int tk = kt * 32 + c31; if (tk > 84) tk = 84;
    ka[kt] = ldg8(Kp + (tok0 + tk) * 16 + hh * 8);
  }
  bf16x8 va[6];
  int dm = lane & 15;
#pragma unroll
  for (int ks = 0; ks < 6; ks++)
    va[ks] = *(const bf16x8*)&vT[dm * PLD + ks * 16 + hh * 8];

#pragma unroll
  for (int qt = 0; qt < 3; qt++) {
    int tq = qt * 32 + c31; if (tq > 84) tq = 84;
    bf16x8 qb = ldg8(Qp + (tok0 + tq) * 16 + hh * 8);
    f32x16 s[3];
#pragma unroll
    for (int kt = 0; kt < 3; kt++) s[kt] = zero16();
#pragma unroll
    for (int kt = 0; kt < 3; kt++) s[kt] = MFMA32(ka[kt], qb, s[kt], 0, 0, 0);
#pragma unroll
    for (int r = 0; r < 16; r++) {
      int krow = 64 + (r & 3) + 8 * (r >> 2) + 4 * hh;
      if (krow > 84) s[2][r] = -3e30f;
    }
    float mx = -3e30f;
#pragma unroll
    for (int kt = 0; kt < 3; kt++)
#pragma unroll
      for (int r = 0; r < 16; r++) mx = fmaxf(mx, s[kt][r]);
    mx = fmaxf(mx, __shfl_xor(mx, 32));
    float sum = 0.f;
#pragma unroll
    for (int kt = 0; kt < 3; kt++)
#pragma unroll
      for (int r = 0; r < 16; r++) { float e = __expf(s[kt][r] - mx); s[kt][r] = e; sum += e; }
    sum += __shfl_xor(sum, 32);
    float inv = 1.f / sum;
    bf16x8 pb[6];
#pragma unroll
    for (int ks = 0; ks < 6; ks++) {
      int kt = ks >> 1;
      int b = 8 * (ks & 1);
      unsigned int u0 = pk2(s[kt][b + 0] * inv, s[kt][b + 1] * inv);
      unsigned int u1 = pk2(s[kt][b + 2] * inv, s[kt][b + 3] * inv);
      unsigned int v0 = pk2(s[kt][b + 4] * inv, s[kt][b + 5] * inv);
      unsigned int v1 = pk2(s[kt][b + 6] * inv, s[kt][b + 7] * inv);
      unsigned int u0x = (unsigned int)__shfl_xor((int)u0, 32);
      unsigned int u1x = (unsigned int)__shfl_xor((int)u1, 32);
      unsigned int v0x = (unsigned int)__shfl_xor((int)v0, 32);
      unsigned int v1x = (unsigned int)__shfl_xor((int)v1, 32);
      unsigned int wv[4];
      wv[0] = hh ? v0x : u0;
      wv[1] = hh ? v1x : u1;
      wv[2] = hh ? v0 : u0x;
      wv[3] = hh ? v1 : u1x;
      __builtin_memcpy(&pb[ks], wv, 16);
    }
    f32x16 o = zero16();
#pragma unroll
    for (int ks = 0; ks < 6; ks++) o = MFMA32(va[ks], pb[ks], o, 0, 0, 0);
#pragma unroll
    for (int r = 0; r < 8; r++) {
      int d = (r & 3) + 8 * (r >> 2) + 4 * hh;
      oT[c31 * 24 + d] = (short)f2b(o[r]);
    }
    int tl = lane >> 1, hf = (lane & 1) * 8;
    int tq2 = qt * 32 + tl;
    if (tq2 < 85) {
      bf16x8 ov = *(const bf16x8*)&oT[tl * 24 + hf];
      *(bf16x8*)&ATB[(tok0 + tq2) * 128 + h * 16 + hf] = ov;
    }
  }
}

// ---------------- proj (K=128, N=128) + residual + fused LN2, swapped --------
__global__ __launch_bounds__(256) void proj_mfma(
    const short* __restrict__ ATB, const short* __restrict__ Wt,
    const float* __restrict__ lng, const float* __restrict__ lnb,
    float* __restrict__ X, short* __restrict__ XB) {
  int wid = threadIdx.x >> 6, lane = threadIdx.x & 63;
  int col15 = lane & 15, kg = lane >> 4;
  size_t tok0 = (size_t)blockIdx.x * 64 + wid * 16;
  const short* abase = ATB + (tok0 + col15) * 128 + kg * 8;
  bf16x8 a[4];
#pragma unroll
  for (int ks = 0; ks < 4; ks++) a[ks] = ldg8(abase + ks * 32);
  size_t row = (tok0 + col15) * 128;
  float vals[8][4];
#pragma unroll
  for (int nt = 0; nt < 8; nt++) {
    const short* bbase = Wt + (size_t)(nt * 16 + col15) * 128 + kg * 8;
    f32x4 acc = (f32x4){0.f, 0.f, 0.f, 0.f};
#pragma unroll
    for (int ks = 0; ks < 4; ks++) acc = MFMA(ldg8(bbase + ks * 32), a[ks], acc, 0, 0, 0);
    float4 xr = *(const float4*)&X[row + nt * 16 + kg * 4];
    vals[nt][0] = acc[0] + xr.x; vals[nt][1] = acc[1] + xr.y;
    vals[nt][2] = acc[2] + xr.z; vals[nt][3] = acc[3] + xr.w;
  }
  float s1 = 0.f, s2 = 0.f;
#pragma unroll
  for (int nt = 0; nt < 8; nt++)
#pragma unroll
    for (int r = 0; r < 4; r++) { float v = vals[nt][r]; s1 += v; s2 += v * v; }
  s1 += __shfl_xor(s1, 16); s2 += __shfl_xor(s2, 16);
  s1 += __shfl_xor(s1, 32); s2 += __shfl_xor(s2, 32);
  float mean = s1 * (1.f / 128.f);
  float inv = rsqrtf(s2 * (1.f / 128.f) - mean * mean + 1e-6f);
#pragma unroll
  for (int nt = 0; nt < 8; nt++) {
    int c0 = nt * 16 + kg * 4;
    float4 g4 = *(const float4*)&lng[c0];
    float4 b4 = *(const float4*)&lnb[c0];
    float4 xs;
    xs.x = vals[nt][0]; xs.y = vals[nt][1]; xs.z = vals[nt][2]; xs.w = vals[nt][3];
    *(float4*)&X[row + c0] = xs;
    *(uint2*)&XB[row + c0] = pk4(
        (vals[nt][0] - mean) * inv * g4.x + b4.x,
        (vals[nt][1] - mean) * inv * g4.y + b4.y,
        (vals[nt][2] - mean) * inv * g4.z + b4.z,
        (vals[nt][3] - mean) * inv * g4.w + b4.w);
  }
}

// ---------------- fused MLP: XB = bf16(relu(XB@W1+b1)@W2 + b2 + X) ----------
// 8 waves / 512 thr; 32-token tiles; W2 slice reg-hoisted, W1 streamed (L2);
// H tile in LDS [32][520] bf16 (row pad -> 2-way-free writes).
#define HLD 520
__global__ __launch_bounds__(512) void ffu_mfma(
    const short* __restrict__ XB, const short* __restrict__ W1t,
    const float* __restrict__ b1, const short* __restrict__ W2t,
    const float* __restrict__ b2, const float* __restrict__ X,
    short* __restrict__ XBo, int ntiles) {
  __shared__ short Hs[32 * HLD];
  int wv = threadIdx.x >> 6, lane = threadIdx.x & 63;
  int col15 = lane & 15, kg = lane >> 4;
  // W2 slice: output cols [wv*16, wv*16+16)
  bf16x8 w2[16];
#pragma unroll
  for (int ks = 0; ks < 16; ks++)
    w2[ks] = ldg8(W2t + (size_t)(wv * 16 + col15) * 512 + ks * 32 + kg * 8);
  float4 b2v = *(const float4*)&b2[wv * 16 + kg * 4];
  for (int t = blockIdx.x; t < ntiles; t += gridDim.x) {
    size_t tok0 = (size_t)t * 32;
    bf16x8 a[2][4];
#pragma unroll
    for (int m = 0; m < 2; m++)
#pragma unroll
      for (int ks = 0; ks < 4; ks++)
        a[m][ks] = ldg8(XB + (tok0 + m * 16 + col15) * 128 + ks * 32 + kg * 8);
    // stage 1: H cols [wv*64, wv*64+64) = relu(XB @ W1 + b1)
    f32x4 acc1[4][2];
#pragma unroll
    for (int nt = 0; nt < 4; nt++)
#pragma unroll
      for (int m = 0; m < 2; m++) acc1[nt][m] = (f32x4){0.f, 0.f, 0.f, 0.f};
#pragma unroll
    for (int nt = 0; nt < 4; nt++)
#pragma unroll
      for (int ks = 0; ks < 4; ks++) {
        bf16x8 w1f = ldg8(W1t + (size_t)(wv * 64 + nt * 16 + col15) * 128 + ks * 32 + kg * 8);
#pragma unroll
        for (int m = 0; m < 2; m++)
          acc1[nt][m] = MFMA(w1f, a[m][ks], acc1[nt][m], 0, 0, 0);
      }
    __syncthreads();  // prior tile's H reads complete
#pragma unroll
    for (int nt = 0; nt < 4; nt++) {
      int c0 = wv * 64 + nt * 16 + kg * 4;
      float4 b1v = *(const float4*)&b1[c0];
#pragma unroll
      for (int m = 0; m < 2; m++) {
        int hrow = m * 16 + col15;
        *(uint2*)&Hs[hrow * HLD + c0] = pk4(
            fmaxf(acc1[nt][m][0] + b1v.x, 0.f), fmaxf(acc1[nt][m][1] + b1v.y, 0.f),
            fmaxf(acc1[nt][m][2] + b1v.z, 0.f), fmaxf(acc1[nt][m][3] + b1v.w, 0.f));
      }
    }
    __syncthreads();  // H tile complete
    // stage 2: out cols [wv*16, wv*16+16) = H @ W2 + b2 + X
    f32x4 acc2[2];
#pragma unroll
    for (int m = 0; m < 2; m++) acc2[m] = (f32x4){0.f, 0.f, 0.f, 0.f};
#pragma unroll
    for (int ks = 0; ks < 16; ks++)
#pragma unroll
      for (int m = 0; m < 2; m++) {
        bf16x8 hhf = *(const bf16x8*)&Hs[(m * 16 + col15) * HLD + ks * 32 + kg * 8];
        acc2[m] = MFMA(w2[ks], hhf, acc2[m], 0, 0, 0);
      }
#pragma unroll
    for (int m = 0; m < 2; m++) {
      size_t row = (tok0 + m * 16 + col15) * 128;
      int c0 = wv * 16 + kg * 4;
      float4 xr = *(const float4*)&X[row + c0];
      *(uint2*)&XBo[row + c0] = pk4(
          xr.x + acc2[m][0] + b2v.x, xr.y + acc2[m][1] + b2v.y,
          xr.z + acc2[m][2] + b2v.z, xr.w + acc2[m][3] + b2v.w);
    }
  }
}

// ---------------- fused un-partition + reverse projection, swapped -----------
struct RevArgs {
  const short* wt[4];
  const float* bias[4];
  float* out[4];
  int hsS[4]; int wsS[4]; int tokOff[4];
  int chShift[4];   // log2 CHout
  int ntcShift[4];  // log2(CHout/32)
};
__global__ __launch_bounds__(256) void rev_all(RevArgs A, const short* __restrict__ XB) {
  int g = blockIdx.x * 4 + (threadIdx.x >> 6);
  int lane = threadIdx.x & 63, col15 = lane & 15, kg = lane >> 4;
  int lvl, lb;
  if (g < 2048) { lvl = 3; lb = g; }
  else if (g < 6144) { lvl = 2; lb = g - 2048; }
  else if (g < 14336) { lvl = 1; lb = g - 6144; }
  else { lvl = 0; lb = g - 14336; }
  int ntcS = A.ntcShift[lvl];
  int tr = lb >> ntcS, tc = lb & ((1 << ntcS) - 1);
  int CHout = 1 << A.chShift[lvl];
  int p0 = tr * 16, c0 = tc * 32;
  int atok = tokmap(p0 + col15, A.hsS[lvl], A.wsS[lvl], A.tokOff[lvl]);
  const short* abase = XB + (size_t)atok * 128 + kg * 8;
  bf16x8 a[4];
#pragma unroll
  for (int ks = 0; ks < 4; ks++) a[ks] = ldg8(abase + ks * 32);
  const short* Wt = A.wt[lvl];
  const float* bias = A.bias[lvl];
  float* out = A.out[lvl];
  size_t orow = (size_t)(p0 + col15) * CHout;
#pragma unroll
  for (int i = 0; i < 2; i++) {
    int col = c0 + i * 16 + col15;
    const short* bbase = Wt + (size_t)col * 128 + kg * 8;
    f32x4 c = (f32x4){0.f, 0.f, 0.f, 0.f};
#pragma unroll
    for (int ks = 0; ks < 4; ks++) c = MFMA(ldg8(bbase + ks * 32), a[ks], c, 0, 0, 0);
    int cc = c0 + i * 16 + kg * 4;
    float4 b4 = *(const float4*)&bias[cc];
    float4 o;
    o.x = c[0] + b4.x; o.y = c[1] + b4.y; o.z = c[2] + b4.z; o.w = c[3] + b4.w;
    *(float4*)&out[orow + cc] = o;
  }
}

extern "C" void kernel_launch(void* const* d_in, const int* in_sizes, int n_in,
                              void* d_out, int out_size, void* d_ws, size_t ws_size,
                              hipStream_t stream) {
  const float* x[4]; const float* fcW[4]; const float* fcb[4];
  const float* revW[4]; const float* revb[4];
  for (int j = 0; j < 4; j++) {
    x[j]    = (const float*)d_in[j * 5 + 0];
    fcW[j]  = (const float*)d_in[j * 5 + 1];
    fcb[j]  = (const float*)d_in[j * 5 + 2];
    revW[j] = (const float*)d_in[j * 5 + 3];
    revb[j] = (const float*)d_in[j * 5 + 4];
  }
  const float* ln1g = (const float*)d_in[20];
  const float* ln1b = (const float*)d_in[21];
  const float* ln2g = (const float*)d_in[22];
  const float* ln2b = (const float*)d_in[23];
  const float* qkvW = (const float*)d_in[24];
  const float* projW = (const float*)d_in[25];
  const float* fc1W = (const float*)d_in[26];
  const float* fc1b = (const float*)d_in[27];
  const float* fc2W = (const float*)d_in[28];
  const float* fc2b = (const float*)d_in[29];

  // workspace layout
  float* X    = (float*)d_ws;                           // NTOK*128 f32
  short* QKVH = (short*)(X + (size_t)NTOK * 128);       // NTOK*384 bf16 (head-major)
  short* XB   = QKVH + (size_t)NTOK * 384;              // NTOK*128 bf16
  short* ATB  = XB + (size_t)NTOK * 128;                // NTOK*128 bf16
  short* XIN  = ATB + (size_t)NTOK * 128;               // scratch
  short* WT   = XIN + (size_t)15728640;                 // 688128 bf16

  static const int CH[4] = {128, 256, 512, 1024};
  static const int hsS[4] = {6, 5, 4, 3};
  static const int wsS[4] = {3, 2, 1, 0};
  static const int tokOff[4] = {0, 64, 80, 84};
  static const int chShift[4] = {7, 8, 9, 10};
  static const int fcWtOff[4] = {0, 16384, 49152, 114688};
  static const int revWtOff[4] = {245760, 262144, 294912, 360448};
  const int qkvWtOff = 491520, projWtOff = 540672, fc1WtOff = 557056, fc2WtOff = 622592;

  PrepW pw;
  int cum = 0;
  auto setw = [&](int idx, const float* src, short* dst, int K, int N) {
    pw.src[idx] = src; pw.dst[idx] = dst;
    int ksh = 0; while ((1 << ksh) < K) ksh++;
    pw.kshift[idx] = ksh; pw.N[idx] = N;
    pw.off[idx] = cum; cum += K * N;
  };
  for (int j = 0; j < 4; j++) setw(j, fcW[j], WT + fcWtOff[j], CH[j], 128);
  for (int j = 0; j < 4; j++) setw(4 + j, revW[j], WT + revWtOff[j], 128, CH[j]);
  setw(8, qkvW, WT + qkvWtOff, 128, 384);
  setw(9, projW, WT + projWtOff, 128, 128);
  setw(10, fc1W, WT + fc1WtOff, 128, 512);
  setw(11, fc2W, WT + fc2WtOff, 512, 128);
  pw.off[12] = cum;
  prep_w_kernel<<<2688, 256, 0, stream>>>(pw);

  // fused fc: [L3:64][L2:256][L1:256][L0:1024] = 1600 blocks
  FcAllArgs fa;
  for (int j = 0; j < 4; j++) {
    fa.xin[j] = x[j];
    fa.wt[j] = WT + fcWtOff[j];
    fa.bias[j] = fcb[j];
    fa.hsS[j] = hsS[j]; fa.wsS[j] = wsS[j];
    fa.tokOff[j] = tokOff[j]; fa.chShift[j] = chShift[j];
  }
  fc_all<<<1600, 256, 0, stream>>>(fa, ln1g, ln1b, X, XB);

  qkv_mfma<<<1024, 256, 0, stream>>>(XB, WT + qkvWtOff, QKVH, NTOK / 32);
  attn_mfma<<<1024 * 8, 64, 0, stream>>>(QKVH, ATB);
  proj_mfma<<<NTOK / 64, 256, 0, stream>>>(ATB, WT + projWtOff, ln2g, ln2b, X, XB);
  // fused MLP, single dispatch (H never touches HBM)
  ffu_mfma<<<680, 512, 0, stream>>>(XB, WT + fc1WtOff, fc1b, WT + fc2WtOff, fc2b, X, XB, NTOK / 32);

  // fused rev: 30720 wave-tiles (L3 first), 4 per block
  RevArgs ra;
  float* out = (float*)d_out;
  static const size_t outOffArr[4] = {0, 8388608, 12582912, 14680064};
  static const int ntcShift[4] = {2, 3, 4, 5};
  for (int j = 0; j < 4; j++) {
    ra.wt[j] = WT + revWtOff[j];
    ra.bias[j] = revb[j];
    ra.out[j] = out + outOffArr[j];
    ra.hsS[j] = hsS[j]; ra.wsS[j] = wsS[j]; ra.tokOff[j] = tokOff[j];
    ra.chShift[j] = chShift[j]; ra.ntcShift[j] = ntcShift[j];
  }
  rev_all<<<7680, 256, 0, stream>>>(ra, XB);
}

// Round 15
// 280.186 us; speedup vs baseline: 1.1535x; 1.0196x over previous
//
#include <hip/hip_runtime.h>
#include <hip/hip_bf16.h>

#define NTOK 87040  // 1024 windows * 85 tokens

typedef __attribute__((ext_vector_type(8))) short bf16x8;
typedef __attribute__((ext_vector_type(4))) float f32x4;
typedef __attribute__((ext_vector_type(16))) float f32x16;

#define MFMA __builtin_amdgcn_mfma_f32_16x16x32_bf16
#define MFMA32 __builtin_amdgcn_mfma_f32_32x32x16_bf16

__device__ __forceinline__ unsigned short f2b(float f) {
  unsigned int u; __builtin_memcpy(&u, &f, 4);
  u += 0x7fffu + ((u >> 16) & 1u);  // RNE
  return (unsigned short)(u >> 16);
}
__device__ __forceinline__ float b2f(short s) {
  unsigned int u = ((unsigned int)(unsigned short)s) << 16;
  float f; __builtin_memcpy(&f, &u, 4);
  return f;
}
__device__ __forceinline__ bf16x8 ldg8(const short* p) { return *(const bf16x8*)p; }
__device__ __forceinline__ f32x16 zero16() {
  f32x16 z;
#pragma unroll
  for (int i = 0; i < 16; i++) z[i] = 0.f;
  return z;
}
__device__ __forceinline__ unsigned int pk2(float lo, float hi) {
  float2 t2; t2.x = lo; t2.y = hi;
  __hip_bfloat162 t = __float22bfloat162_rn(t2);
  unsigned int r; __builtin_memcpy(&r, &t, 4);
  return r;
}
__device__ __forceinline__ uint2 pk4(float a, float b, float c, float d) {
  uint2 r; r.x = pk2(a, b); r.y = pk2(c, d);
  return r;
}
// unpack 4 bf16 (uint2) -> float4
__device__ __forceinline__ float4 ub4(uint2 u) {
  float4 f;
  f.x = b2f((short)(u.x & 0xffff)); f.y = b2f((short)(u.x >> 16));
  f.z = b2f((short)(u.y & 0xffff)); f.w = b2f((short)(u.y >> 16));
  return f;
}
// load 8 f32, convert to bf16x8 fragment (RNE, same as prep path)
__device__ __forceinline__ bf16x8 ldf8(const float* p) {
  float4 a = *(const float4*)p;
  float4 b = *(const float4*)(p + 4);
  unsigned int w[4] = {pk2(a.x, a.y), pk2(a.z, a.w), pk2(b.x, b.y), pk2(b.z, b.w)};
  bf16x8 o; __builtin_memcpy(&o, w, 16);
  return o;
}

// natural spatial row p -> window token index
__device__ __forceinline__ int tokmap(int p, int hsShift, int wsShift, int tokOff) {
  int HSm = (1 << hsShift) - 1;
  int w = p & HSm;
  int h = (p >> hsShift) & HSm;
  int b = p >> (2 * hsShift);
  int bi = h >> wsShift, bj = w >> wsShift;
  int wsm = (1 << wsShift) - 1;
  int tt = ((h & wsm) << wsShift) + (w & wsm);
  return ((((b << 3) | bi) << 3) | bj) * 85 + tokOff + tt;
}

// ---------------- weights: fp32 [K][N] -> bf16 [N][K] ----------------
struct PrepW {
  const float* src[12];
  short* dst[12];
  int kshift[12];
  int N[12];
  int off[13];
};
__global__ __launch_bounds__(256) void prep_w_kernel(PrepW p) {
  int i = blockIdx.x * 256 + threadIdx.x;
  int s = 0;
#pragma unroll
  for (int t = 0; t < 12; t++) if (i >= p.off[t + 1]) s = t + 1;
  if (s >= 12) return;
  int e = i - p.off[s];
  int K = 1 << p.kshift[s];
  int n = e >> p.kshift[s];
  int k = e & (K - 1);
  p.dst[s][e] = (short)f2b(p.src[s][(size_t)k * p.N[s] + n]);
}

// ---------------- fused fc (all 4 levels, f32 input) + partition + LN1 -------
// blocks [0,64): lvl3 split-K; [64,320): lvl2 split-K; [320,576): lvl1;
// [576,1600): lvl0, 1 tile/wave, weights hoisted to registers.
// Residual stream XR is bf16 (threshold headroom 3.6x permits).
struct FcAllArgs {
  const float* xin[4];
  const short* wt[4];
  const float* bias[4];
  int hsS[4]; int wsS[4]; int tokOff[4]; int chShift[4];
};
__global__ __launch_bounds__(256) void fc_all(
    FcAllArgs A, const float* __restrict__ lng, const float* __restrict__ lnb,
    short* __restrict__ XR, short* __restrict__ XB) {
  __shared__ float red[4][16 * 129];
  int bid = blockIdx.x;
  int wv = threadIdx.x >> 6, lane = threadIdx.x & 63;
  int col15 = lane & 15, kg = lane >> 4;

  if (bid >= 576) {
    // ---- lvl0: 1024 blocks x 4 waves, 1 tile of 16 tokens per wave ----
    const float* XIN = A.xin[0];
    const short* Wt = A.wt[0];
    const float* bias = A.bias[0];
    int hsShift = A.hsS[0], wsShift = A.wsS[0], tokOff = A.tokOff[0];
    bf16x8 w[8][4];
#pragma unroll
    for (int nt = 0; nt < 8; nt++)
#pragma unroll
      for (int ks = 0; ks < 4; ks++)
        w[nt][ks] = ldg8(Wt + (size_t)(nt * 16 + col15) * 128 + ks * 32 + kg * 8);
    int t = (bid - 576) * 4 + wv;  // 0..4095
    int p0 = t * 16;
    const float* abase = XIN + (size_t)(p0 + col15) * 128 + kg * 8;
    bf16x8 a[4];
#pragma unroll
    for (int ks = 0; ks < 4; ks++) a[ks] = ldf8(abase + ks * 32);
    f32x4 c[8];
#pragma unroll
    for (int nt = 0; nt < 8; nt++) c[nt] = (f32x4){0.f, 0.f, 0.f, 0.f};
#pragma unroll
    for (int nt = 0; nt < 8; nt++)
#pragma unroll
      for (int ks = 0; ks < 4; ks++)
        c[nt] = MFMA(w[nt][ks], a[ks], c[nt], 0, 0, 0);  // swapped
    float vals[8][4];
#pragma unroll
    for (int nt = 0; nt < 8; nt++) {
      float4 bb = *(const float4*)&bias[nt * 16 + kg * 4];
      vals[nt][0] = c[nt][0] + bb.x; vals[nt][1] = c[nt][1] + bb.y;
      vals[nt][2] = c[nt][2] + bb.z; vals[nt][3] = c[nt][3] + bb.w;
    }
    float s1 = 0.f, s2 = 0.f;
#pragma unroll
    for (int nt = 0; nt < 8; nt++)
#pragma unroll
      for (int r = 0; r < 4; r++) { float v = vals[nt][r]; s1 += v; s2 += v * v; }
    s1 += __shfl_xor(s1, 16); s2 += __shfl_xor(s2, 16);
    s1 += __shfl_xor(s1, 32); s2 += __shfl_xor(s2, 32);
    float mean = s1 * (1.f / 128.f);
    float inv = rsqrtf(s2 * (1.f / 128.f) - mean * mean + 1e-6f);
    size_t row = (size_t)tokmap(p0 + col15, hsShift, wsShift, tokOff) * 128;
#pragma unroll
    for (int nt = 0; nt < 8; nt++) {
      int c0 = nt * 16 + kg * 4;
      float4 g4 = *(const float4*)&lng[c0];
      float4 b4 = *(const float4*)&lnb[c0];
      *(uint2*)&XR[row + c0] = pk4(vals[nt][0], vals[nt][1], vals[nt][2], vals[nt][3]);
      *(uint2*)&XB[row + c0] = pk4(
          (vals[nt][0] - mean) * inv * g4.x + b4.x,
          (vals[nt][1] - mean) * inv * g4.y + b4.y,
          (vals[nt][2] - mean) * inv * g4.z + b4.z,
          (vals[nt][3] - mean) * inv * g4.w + b4.w);
    }
    return;
  }

  int lvl, lb;
  if (bid < 64) { lvl = 3; lb = bid; }
  else if (bid < 320) { lvl = 2; lb = bid - 64; }
  else { lvl = 1; lb = bid - 320; }
  const float* XIN = A.xin[lvl];
  const short* Wt = A.wt[lvl];
  const float* bias = A.bias[lvl];
  int CH = 1 << A.chShift[lvl];
  int hsShift = A.hsS[lvl], wsShift = A.wsS[lvl], tokOff = A.tokOff[lvl];

  if (lvl >= 2) {
    // ---- 16-token block, 4-way split-K ----
    int p0 = lb * 16;
    int kb = wv * (CH >> 2);
    const float* abase = XIN + (size_t)(p0 + col15) * CH + kb + kg * 8;
    f32x4 c[8];
#pragma unroll
    for (int nt = 0; nt < 8; nt++) c[nt] = (f32x4){0.f, 0.f, 0.f, 0.f};
    int kiters = CH >> 7;
    for (int ks = 0; ks < kiters; ks++) {
      bf16x8 a = ldf8(abase + ks * 32);
#pragma unroll
      for (int nt = 0; nt < 8; nt++) {
        bf16x8 b = ldg8(Wt + (size_t)(nt * 16 + col15) * CH + kb + ks * 32 + kg * 8);
        c[nt] = MFMA(b, a, c[nt], 0, 0, 0);  // swapped: C[col=token]
      }
    }
    // red[token=col15][col=nt*16+kg*4+r]
#pragma unroll
    for (int nt = 0; nt < 8; nt++)
#pragma unroll
      for (int r = 0; r < 4; r++)
        red[wv][col15 * 129 + nt * 16 + kg * 4 + r] = c[nt][r];
    __syncthreads();
    // finish: wave wv handles tokens wv*4..wv*4+3 (kg selects token)
    int tt = wv * 4 + kg;
    float v[8], gv[8], bv[8];
#pragma unroll
    for (int nt = 0; nt < 8; nt++) {
      int col = nt * 16 + col15;
      v[nt] = red[0][tt * 129 + col] + red[1][tt * 129 + col] +
              red[2][tt * 129 + col] + red[3][tt * 129 + col] + bias[col];
      gv[nt] = lng[col]; bv[nt] = lnb[col];
    }
    float s1 = 0.f, s2 = 0.f;
#pragma unroll
    for (int nt = 0; nt < 8; nt++) { s1 += v[nt]; s2 += v[nt] * v[nt]; }
#pragma unroll
    for (int m = 1; m < 16; m <<= 1) { s1 += __shfl_xor(s1, m); s2 += __shfl_xor(s2, m); }
    float mean = s1 * (1.f / 128.f);
    float inv = rsqrtf(s2 * (1.f / 128.f) - mean * mean + 1e-6f);
    size_t row = (size_t)tokmap(p0 + tt, hsShift, wsShift, tokOff) * 128;
#pragma unroll
    for (int nt = 0; nt < 8; nt++) {
      int col = nt * 16 + col15;
      XR[row + col] = (short)f2b(v[nt]);
      XB[row + col] = (short)f2b((v[nt] - mean) * inv * gv[nt] + bv[nt]);
    }
  } else {
    // ---- lvl1: 64-token block, full K per wave ----
    int p0 = lb * 64 + wv * 16;
    const float* abase = XIN + (size_t)(p0 + col15) * CH + kg * 8;
    f32x4 c[8];
#pragma unroll
    for (int nt = 0; nt < 8; nt++) c[nt] = (f32x4){0.f, 0.f, 0.f, 0.f};
    int kiters = CH >> 5;
    for (int ks = 0; ks < kiters; ks++) {
      bf16x8 a = ldf8(abase + ks * 32);
#pragma unroll
      for (int nt = 0; nt < 8; nt++) {
        bf16x8 b = ldg8(Wt + (size_t)(nt * 16 + col15) * CH + ks * 32 + kg * 8);
        c[nt] = MFMA(b, a, c[nt], 0, 0, 0);  // swapped
      }
    }
    float vals[8][4];
#pragma unroll
    for (int nt = 0; nt < 8; nt++) {
      float4 bb = *(const float4*)&bias[nt * 16 + kg * 4];
#pragma unroll
      for (int r = 0; r < 4; r++) vals[nt][r] = c[nt][r] + ((const float*)&bb)[r];
    }
    float s1 = 0.f, s2 = 0.f;
#pragma unroll
    for (int nt = 0; nt < 8; nt++)
#pragma unroll
      for (int r = 0; r < 4; r++) { float v = vals[nt][r]; s1 += v; s2 += v * v; }
    s1 += __shfl_xor(s1, 16); s2 += __shfl_xor(s2, 16);
    s1 += __shfl_xor(s1, 32); s2 += __shfl_xor(s2, 32);
    float mean = s1 * (1.f / 128.f);
    float inv = rsqrtf(s2 * (1.f / 128.f) - mean * mean + 1e-6f);
    size_t row = (size_t)tokmap(p0 + col15, hsShift, wsShift, tokOff) * 128;
#pragma unroll
    for (int nt = 0; nt < 8; nt++) {
      int c0 = nt * 16 + kg * 4;
      float4 g4 = *(const float4*)&lng[c0];
      float4 b4 = *(const float4*)&lnb[c0];
      float n0 = (vals[nt][0] - mean) * inv * g4.x + b4.x;
      float n1 = (vals[nt][1] - mean) * inv * g4.y + b4.y;
      float n2 = (vals[nt][2] - mean) * inv * g4.z + b4.z;
      float n3 = (vals[nt][3] - mean) * inv * g4.w + b4.w;
      *(uint2*)&XR[row + c0] = pk4(vals[nt][0], vals[nt][1], vals[nt][2], vals[nt][3]);
      *(uint2*)&XB[row + c0] = pk4(n0, n1, n2, n3);
    }
  }
}

// ---------------- QKV (K=128, N=384): persistent, swapped ----------------
// QKVH layout: [which(3)][head(8)][NTOK][16]
__global__ __launch_bounds__(256) void qkv_mfma(
    const short* __restrict__ XB, const short* __restrict__ Wt,
    short* __restrict__ QKVH, int ntiles) {
  int wv = threadIdx.x >> 6, lane = threadIdx.x & 63;
  int col15 = lane & 15, kg = lane >> 4;
  bf16x8 w[6][4];
#pragma unroll
  for (int i = 0; i < 6; i++)
#pragma unroll
    for (int ks = 0; ks < 4; ks++)
      w[i][ks] = ldg8(Wt + (size_t)((wv * 6 + i) * 16 + col15) * 128 + ks * 32 + kg * 8);
  for (int t = blockIdx.x; t < ntiles; t += gridDim.x) {
    size_t tok0 = (size_t)t * 32;
    bf16x8 a[2][4];
#pragma unroll
    for (int m = 0; m < 2; m++)
#pragma unroll
      for (int ks = 0; ks < 4; ks++)
        a[m][ks] = ldg8(XB + (tok0 + m * 16 + col15) * 128 + ks * 32 + kg * 8);
    f32x4 acc[6][2];
#pragma unroll
    for (int i = 0; i < 6; i++)
#pragma unroll
      for (int m = 0; m < 2; m++) acc[i][m] = (f32x4){0.f, 0.f, 0.f, 0.f};
#pragma unroll
    for (int i = 0; i < 6; i++)
#pragma unroll
      for (int m = 0; m < 2; m++)
#pragma unroll
        for (int ks = 0; ks < 4; ks++)
          acc[i][m] = MFMA(w[i][ks], a[m][ks], acc[i][m], 0, 0, 0);  // swapped
#pragma unroll
    for (int i = 0; i < 6; i++) {
      size_t hb = (size_t)(wv * 6 + i) * NTOK;
#pragma unroll
      for (int m = 0; m < 2; m++) {
        size_t tok = tok0 + m * 16 + col15;
        *(uint2*)&QKVH[(hb + tok) * 16 + kg * 4] =
            pk4(acc[i][m][0], acc[i][m][1], acc[i][m][2], acc[i][m][3]);
      }
    }
  }
}

// ---------------- MFMA attention, 32x32x16 swapped-operand form --------------
#define PLD 104
__global__ __launch_bounds__(64) void attn_mfma(
    const short* __restrict__ QKVH, short* __restrict__ ATB) {
  int blk = blockIdx.x;
  int h = blk & 7, sb = blk >> 3;
  size_t tok0 = (size_t)sb * 85;
  __shared__ short vT[16 * PLD];  // V^T [d][tok], zero-padded to 96
  __shared__ short oT[32 * 24];   // O^T bounce [q][d], row stride 24 elems
  int lane = threadIdx.x;
  int c31 = lane & 31, hh = lane >> 5;
  const short* Qp = QKVH + (size_t)h * NTOK * 16;
  const short* Kp = QKVH + (size_t)(8 + h) * NTOK * 16;
  const short* Vp = QKVH + (size_t)(16 + h) * NTOK * 16;

#pragma unroll
  for (int i = 0; i < 3; i++) {
    int idx = i * 64 + lane;
    if (idx < 170) {
      int m = idx >> 1, half = (idx & 1) << 3;
      bf16x8 v = ldg8(Vp + (tok0 + m) * 16 + half);
#pragma unroll
      for (int j = 0; j < 8; j++) vT[(half + j) * PLD + m] = v[j];
    }
  }
  for (int i = lane; i < 176; i += 64) {
    int d = i / 11, m = 85 + i % 11;
    vT[d * PLD + m] = 0;
  }

  bf16x8 ka[3];
#pragma unroll
  for (int kt = 0; kt < 3; kt++) {
    int tk = kt * 32 + c31; if (tk > 84) tk = 84;
    ka[kt] = ldg8(Kp + (tok0 + tk) * 16 + hh * 8);
  }
  bf16x8 va[6];
  int dm = lane & 15;
#pragma unroll
  for (int ks = 0; ks < 6; ks++)
    va[ks] = *(const bf16x8*)&vT[dm * PLD + ks * 16 + hh * 8];

#pragma unroll
  for (int qt = 0; qt < 3; qt++) {
    int tq = qt * 32 + c31; if (tq > 84) tq = 84;
    bf16x8 qb = ldg8(Qp + (tok0 + tq) * 16 + hh * 8);
    f32x16 s[3];
#pragma unroll
    for (int kt = 0; kt < 3; kt++) s[kt] = zero16();
#pragma unroll
    for (int kt = 0; kt < 3; kt++) s[kt] = MFMA32(ka[kt], qb, s[kt], 0, 0, 0);
#pragma unroll
    for (int r = 0; r < 16; r++) {
      int krow = 64 + (r & 3) + 8 * (r >> 2) + 4 * hh;
      if (krow > 84) s[2][r] = -3e30f;
    }
    float mx = -3e30f;
#pragma unroll
    for (int kt = 0; kt < 3; kt++)
#pragma unroll
      for (int r = 0; r < 16; r++) mx = fmaxf(mx, s[kt][r]);
    mx = fmaxf(mx, __shfl_xor(mx, 32));
    float sum = 0.f;
#pragma unroll
    for (int kt = 0; kt < 3; kt++)
#pragma unroll
      for (int r = 0; r < 16; r++) { float e = __expf(s[kt][r] - mx); s[kt][r] = e; sum += e; }
    sum += __shfl_xor(sum, 32);
    float inv = 1.f / sum;
    bf16x8 pb[6];
#pragma unroll
    for (int ks = 0; ks < 6; ks++) {
      int kt = ks >> 1;
      int b = 8 * (ks & 1);
      unsigned int u0 = pk2(s[kt][b + 0] * inv, s[kt][b + 1] * inv);
      unsigned int u1 = pk2(s[kt][b + 2] * inv, s[kt][b + 3] * inv);
      unsigned int v0 = pk2(s[kt][b + 4] * inv, s[kt][b + 5] * inv);
      unsigned int v1 = pk2(s[kt][b + 6] * inv, s[kt][b + 7] * inv);
      unsigned int u0x = (unsigned int)__shfl_xor((int)u0, 32);
      unsigned int u1x = (unsigned int)__shfl_xor((int)u1, 32);
      unsigned int v0x = (unsigned int)__shfl_xor((int)v0, 32);
      unsigned int v1x = (unsigned int)__shfl_xor((int)v1, 32);
      unsigned int wv[4];
      wv[0] = hh ? v0x : u0;
      wv[1] = hh ? v1x : u1;
      wv[2] = hh ? v0 : u0x;
      wv[3] = hh ? v1 : u1x;
      __builtin_memcpy(&pb[ks], wv, 16);
    }
    f32x16 o = zero16();
#pragma unroll
    for (int ks = 0; ks < 6; ks++) o = MFMA32(va[ks], pb[ks], o, 0, 0, 0);
#pragma unroll
    for (int r = 0; r < 8; r++) {
      int d = (r & 3) + 8 * (r >> 2) + 4 * hh;
      oT[c31 * 24 + d] = (short)f2b(o[r]);
    }
    int tl = lane >> 1, hf = (lane & 1) * 8;
    int tq2 = qt * 32 + tl;
    if (tq2 < 85) {
      bf16x8 ov = *(const bf16x8*)&oT[tl * 24 + hf];
      *(bf16x8*)&ATB[(tok0 + tq2) * 128 + h * 16 + hf] = ov;
    }
  }
}

// ---------------- proj (K=128, N=128) + residual(bf16) + fused LN2 -----------
__global__ __launch_bounds__(256) void proj_mfma(
    const short* __restrict__ ATB, const short* __restrict__ Wt,
    const float* __restrict__ lng, const float* __restrict__ lnb,
    short* __restrict__ XR, short* __restrict__ XB) {
  int wid = threadIdx.x >> 6, lane = threadIdx.x & 63;
  int col15 = lane & 15, kg = lane >> 4;
  size_t tok0 = (size_t)blockIdx.x * 64 + wid * 16;
  const short* abase = ATB + (tok0 + col15) * 128 + kg * 8;
  bf16x8 a[4];
#pragma unroll
  for (int ks = 0; ks < 4; ks++) a[ks] = ldg8(abase + ks * 32);
  size_t row = (tok0 + col15) * 128;
  float vals[8][4];
#pragma unroll
  for (int nt = 0; nt < 8; nt++) {
    const short* bbase = Wt + (size_t)(nt * 16 + col15) * 128 + kg * 8;
    f32x4 acc = (f32x4){0.f, 0.f, 0.f, 0.f};
#pragma unroll
    for (int ks = 0; ks < 4; ks++) acc = MFMA(ldg8(bbase + ks * 32), a[ks], acc, 0, 0, 0);
    float4 xr = ub4(*(const uint2*)&XR[row + nt * 16 + kg * 4]);
    vals[nt][0] = acc[0] + xr.x; vals[nt][1] = acc[1] + xr.y;
    vals[nt][2] = acc[2] + xr.z; vals[nt][3] = acc[3] + xr.w;
  }
  float s1 = 0.f, s2 = 0.f;
#pragma unroll
  for (int nt = 0; nt < 8; nt++)
#pragma unroll
    for (int r = 0; r < 4; r++) { float v = vals[nt][r]; s1 += v; s2 += v * v; }
  s1 += __shfl_xor(s1, 16); s2 += __shfl_xor(s2, 16);
  s1 += __shfl_xor(s1, 32); s2 += __shfl_xor(s2, 32);
  float mean = s1 * (1.f / 128.f);
  float inv = rsqrtf(s2 * (1.f / 128.f) - mean * mean + 1e-6f);
#pragma unroll
  for (int nt = 0; nt < 8; nt++) {
    int c0 = nt * 16 + kg * 4;
    float4 g4 = *(const float4*)&lng[c0];
    float4 b4 = *(const float4*)&lnb[c0];
    *(uint2*)&XR[row + c0] = pk4(vals[nt][0], vals[nt][1], vals[nt][2], vals[nt][3]);
    *(uint2*)&XB[row + c0] = pk4(
        (vals[nt][0] - mean) * inv * g4.x + b4.x,
        (vals[nt][1] - mean) * inv * g4.y + b4.y,
        (vals[nt][2] - mean) * inv * g4.z + b4.z,
        (vals[nt][3] - mean) * inv * g4.w + b4.w);
  }
}

// ---------------- fused MLP: XB = bf16(relu(XB@W1+b1)@W2 + b2 + XR) ---------
// 8 waves / 512 thr; 32-token tiles; W2 slice reg-hoisted, W1 streamed (L2);
// H tile in LDS [32][520] bf16 (row pad -> 2-way-free writes).
#define HLD 520
__global__ __launch_bounds__(512) void ffu_mfma(
    const short* __restrict__ XB, const short* __restrict__ W1t,
    const float* __restrict__ b1, const short* __restrict__ W2t,
    const float* __restrict__ b2, const short* __restrict__ XR,
    short* __restrict__ XBo, int ntiles) {
  __shared__ short Hs[32 * HLD];
  int wv = threadIdx.x >> 6, lane = threadIdx.x & 63;
  int col15 = lane & 15, kg = lane >> 4;
  // W2 slice: output cols [wv*16, wv*16+16)
  bf16x8 w2[16];
#pragma unroll
  for (int ks = 0; ks < 16; ks++)
    w2[ks] = ldg8(W2t + (size_t)(wv * 16 + col15) * 512 + ks * 32 + kg * 8);
  float4 b2v = *(const float4*)&b2[wv * 16 + kg * 4];
  for (int t = blockIdx.x; t < ntiles; t += gridDim.x) {
    size_t tok0 = (size_t)t * 32;
    bf16x8 a[2][4];
#pragma unroll
    for (int m = 0; m < 2; m++)
#pragma unroll
      for (int ks = 0; ks < 4; ks++)
        a[m][ks] = ldg8(XB + (tok0 + m * 16 + col15) * 128 + ks * 32 + kg * 8);
    // stage 1: H cols [wv*64, wv*64+64) = relu(XB @ W1 + b1)
    f32x4 acc1[4][2];
#pragma unroll
    for (int nt = 0; nt < 4; nt++)
#pragma unroll
      for (int m = 0; m < 2; m++) acc1[nt][m] = (f32x4){0.f, 0.f, 0.f, 0.f};
#pragma unroll
    for (int nt = 0; nt < 4; nt++)
#pragma unroll
      for (int ks = 0; ks < 4; ks++) {
        bf16x8 w1f = ldg8(W1t + (size_t)(wv * 64 + nt * 16 + col15) * 128 + ks * 32 + kg * 8);
#pragma unroll
        for (int m = 0; m < 2; m++)
          acc1[nt][m] = MFMA(w1f, a[m][ks], acc1[nt][m], 0, 0, 0);
      }
    __syncthreads();  // prior tile's H reads complete
#pragma unroll
    for (int nt = 0; nt < 4; nt++) {
      int c0 = wv * 64 + nt * 16 + kg * 4;
      float4 b1v = *(const float4*)&b1[c0];
#pragma unroll
      for (int m = 0; m < 2; m++) {
        int hrow = m * 16 + col15;
        *(uint2*)&Hs[hrow * HLD + c0] = pk4(
            fmaxf(acc1[nt][m][0] + b1v.x, 0.f), fmaxf(acc1[nt][m][1] + b1v.y, 0.f),
            fmaxf(acc1[nt][m][2] + b1v.z, 0.f), fmaxf(acc1[nt][m][3] + b1v.w, 0.f));
      }
    }
    __syncthreads();  // H tile complete
    // stage 2: out cols [wv*16, wv*16+16) = H @ W2 + b2 + XR
    f32x4 acc2[2];
#pragma unroll
    for (int m = 0; m < 2; m++) acc2[m] = (f32x4){0.f, 0.f, 0.f, 0.f};
#pragma unroll
    for (int ks = 0; ks < 16; ks++)
#pragma unroll
      for (int m = 0; m < 2; m++) {
        bf16x8 hhf = *(const bf16x8*)&Hs[(m * 16 + col15) * HLD + ks * 32 + kg * 8];
        acc2[m] = MFMA(w2[ks], hhf, acc2[m], 0, 0, 0);
      }
#pragma unroll
    for (int m = 0; m < 2; m++) {
      size_t row = (tok0 + m * 16 + col15) * 128;
      int c0 = wv * 16 + kg * 4;
      float4 xr = ub4(*(const uint2*)&XR[row + c0]);
      *(uint2*)&XBo[row + c0] = pk4(
          xr.x + acc2[m][0] + b2v.x, xr.y + acc2[m][1] + b2v.y,
          xr.z + acc2[m][2] + b2v.z, xr.w + acc2[m][3] + b2v.w);
    }
  }
}

// ---------------- fused un-partition + reverse projection, swapped -----------
struct RevArgs {
  const short* wt[4];
  const float* bias[4];
  float* out[4];
  int hsS[4]; int wsS[4]; int tokOff[4];
  int chShift[4];   // log2 CHout
  int ntcShift[4];  // log2(CHout/32)
};
__global__ __launch_bounds__(256) void rev_all(RevArgs A, const short* __restrict__ XB) {
  int g = blockIdx.x * 4 + (threadIdx.x >> 6);
  int lane = threadIdx.x & 63, col15 = lane & 15, kg = lane >> 4;
  int lvl, lb;
  if (g < 2048) { lvl = 3; lb = g; }
  else if (g < 6144) { lvl = 2; lb = g - 2048; }
  else if (g < 14336) { lvl = 1; lb = g - 6144; }
  else { lvl = 0; lb = g - 14336; }
  int ntcS = A.ntcShift[lvl];
  int tr = lb >> ntcS, tc = lb & ((1 << ntcS) - 1);
  int CHout = 1 << A.chShift[lvl];
  int p0 = tr * 16, c0 = tc * 32;
  int atok = tokmap(p0 + col15, A.hsS[lvl], A.wsS[lvl], A.tokOff[lvl]);
  const short* abase = XB + (size_t)atok * 128 + kg * 8;
  bf16x8 a[4];
#pragma unroll
  for (int ks = 0; ks < 4; ks++) a[ks] = ldg8(abase + ks * 32);
  const short* Wt = A.wt[lvl];
  const float* bias = A.bias[lvl];
  float* out = A.out[lvl];
  size_t orow = (size_t)(p0 + col15) * CHout;
#pragma unroll
  for (int i = 0; i < 2; i++) {
    int col = c0 + i * 16 + col15;
    const short* bbase = Wt + (size_t)col * 128 + kg * 8;
    f32x4 c = (f32x4){0.f, 0.f, 0.f, 0.f};
#pragma unroll
    for (int ks = 0; ks < 4; ks++) c = MFMA(ldg8(bbase + ks * 32), a[ks], c, 0, 0, 0);
    int cc = c0 + i * 16 + kg * 4;
    float4 b4 = *(const float4*)&bias[cc];
    float4 o;
    o.x = c[0] + b4.x; o.y = c[1] + b4.y; o.z = c[2] + b4.z; o.w = c[3] + b4.w;
    *(float4*)&out[orow + cc] = o;
  }
}

extern "C" void kernel_launch(void* const* d_in, const int* in_sizes, int n_in,
                              void* d_out, int out_size, void* d_ws, size_t ws_size,
                              hipStream_t stream) {
  const float* x[4]; const float* fcW[4]; const float* fcb[4];
  const float* revW[4]; const float* revb[4];
  for (int j = 0; j < 4; j++) {
    x[j]    = (const float*)d_in[j * 5 + 0];
    fcW[j]  = (const float*)d_in[j * 5 + 1];
    fcb[j]  = (const float*)d_in[j * 5 + 2];
    revW[j] = (const float*)d_in[j * 5 + 3];
    revb[j] = (const float*)d_in[j * 5 + 4];
  }
  const float* ln1g = (const float*)d_in[20];
  const float* ln1b = (const float*)d_in[21];
  const float* ln2g = (const float*)d_in[22];
  const float* ln2b = (const float*)d_in[23];
  const float* qkvW = (const float*)d_in[24];
  const float* projW = (const float*)d_in[25];
  const float* fc1W = (const float*)d_in[26];
  const float* fc1b = (const float*)d_in[27];
  const float* fc2W = (const float*)d_in[28];
  const float* fc2b = (const float*)d_in[29];

  // workspace layout (XR bf16 occupies the old f32-X region)
  short* XR   = (short*)d_ws;                           // NTOK*128 bf16 residual
  short* QKVH = (short*)((float*)d_ws + (size_t)NTOK * 128);  // NTOK*384 bf16
  short* XB   = QKVH + (size_t)NTOK * 384;              // NTOK*128 bf16
  short* ATB  = XB + (size_t)NTOK * 128;                // NTOK*128 bf16
  short* XIN  = ATB + (size_t)NTOK * 128;               // scratch
  short* WT   = XIN + (size_t)15728640;                 // 688128 bf16

  static const int CH[4] = {128, 256, 512, 1024};
  static const int hsS[4] = {6, 5, 4, 3};
  static const int wsS[4] = {3, 2, 1, 0};
  static const int tokOff[4] = {0, 64, 80, 84};
  static const int chShift[4] = {7, 8, 9, 10};
  static const int fcWtOff[4] = {0, 16384, 49152, 114688};
  static const int revWtOff[4] = {245760, 262144, 294912, 360448};
  const int qkvWtOff = 491520, projWtOff = 540672, fc1WtOff = 557056, fc2WtOff = 622592;

  PrepW pw;
  int cum = 0;
  auto setw = [&](int idx, const float* src, short* dst, int K, int N) {
    pw.src[idx] = src; pw.dst[idx] = dst;
    int ksh = 0; while ((1 << ksh) < K) ksh++;
    pw.kshift[idx] = ksh; pw.N[idx] = N;
    pw.off[idx] = cum; cum += K * N;
  };
  for (int j = 0; j < 4; j++) setw(j, fcW[j], WT + fcWtOff[j], CH[j], 128);
  for (int j = 0; j < 4; j++) setw(4 + j, revW[j], WT + revWtOff[j], 128, CH[j]);
  setw(8, qkvW, WT + qkvWtOff, 128, 384);
  setw(9, projW, WT + projWtOff, 128, 128);
  setw(10, fc1W, WT + fc1WtOff, 128, 512);
  setw(11, fc2W, WT + fc2WtOff, 512, 128);
  pw.off[12] = cum;
  prep_w_kernel<<<2688, 256, 0, stream>>>(pw);

  // fused fc: [L3:64][L2:256][L1:256][L0:1024] = 1600 blocks
  FcAllArgs fa;
  for (int j = 0; j < 4; j++) {
    fa.xin[j] = x[j];
    fa.wt[j] = WT + fcWtOff[j];
    fa.bias[j] = fcb[j];
    fa.hsS[j] = hsS[j]; fa.wsS[j] = wsS[j];
    fa.tokOff[j] = tokOff[j]; fa.chShift[j] = chShift[j];
  }
  fc_all<<<1600, 256, 0, stream>>>(fa, ln1g, ln1b, XR, XB);

  qkv_mfma<<<1024, 256, 0, stream>>>(XB, WT + qkvWtOff, QKVH, NTOK / 32);
  attn_mfma<<<1024 * 8, 64, 0, stream>>>(QKVH, ATB);
  proj_mfma<<<NTOK / 64, 256, 0, stream>>>(ATB, WT + projWtOff, ln2g, ln2b, XR, XB);
  // fused MLP, single dispatch (H never touches HBM)
  ffu_mfma<<<680, 512, 0, stream>>>(XB, WT + fc1WtOff, fc1b, WT + fc2WtOff, fc2b, XR, XB, NTOK / 32);

  // fused rev: 30720 wave-tiles (L3 first), 4 per block
  RevArgs ra;
  float* out = (float*)d_out;
  static const size_t outOffArr[4] = {0, 8388608, 12582912, 14680064};
  static const int ntcShift[4] = {2, 3, 4, 5};
  for (int j = 0; j < 4; j++) {
    ra.wt[j] = WT + revWtOff[j];
    ra.bias[j] = revb[j];
    ra.out[j] = out + outOffArr[j];
    ra.hsS[j] = hsS[j]; ra.wsS[j] = wsS[j]; ra.tokOff[j] = tokOff[j];
    ra.chShift[j] = chShift[j]; ra.ntcShift[j] = ntcShift[j];
  }
  rev_all<<<7680, 256, 0, stream>>>(ra, XB);
}